// Round 14
// baseline (177.615 us; speedup 1.0000x reference)
//
#include <hip/hip_runtime.h>

typedef __bf16 bf16x8 __attribute__((ext_vector_type(8)));
typedef float f32x4 __attribute__((ext_vector_type(4)));
typedef float fl4 __attribute__((ext_vector_type(4)));
typedef unsigned short us4 __attribute__((ext_vector_type(4)));
typedef unsigned short us8 __attribute__((ext_vector_type(8)));

__device__ __forceinline__ unsigned short f2bf(float f) {
  unsigned u = __builtin_bit_cast(unsigned, f);
  u += 0x7fffu + ((u >> 16) & 1u);
  return (unsigned short)(u >> 16);
}
__device__ __forceinline__ float bf2f(unsigned short h) {
  unsigned u = ((unsigned)h) << 16;
  return __builtin_bit_cast(float, u);
}

__device__ __forceinline__ void async16(const void* g, void* l) {
  __builtin_amdgcn_global_load_lds(
      (const __attribute__((address_space(1))) unsigned int*)g,
      (__attribute__((address_space(3))) unsigned int*)l, 16, 0, 0);
}

#define BARM() asm volatile("s_barrier" ::: "memory")
#define VMCNT3() asm volatile("s_waitcnt vmcnt(3)" ::: "memory")
#define VMCNT4() asm volatile("s_waitcnt vmcnt(4)" ::: "memory")
#define VMCNT8() asm volatile("s_waitcnt vmcnt(8)" ::: "memory")
#define LGKM0() asm volatile("s_waitcnt lgkmcnt(0)" ::: "memory")
#define LGKM8() asm volatile("s_waitcnt lgkmcnt(8)" ::: "memory")
#define SCHEDB() __builtin_amdgcn_sched_barrier(0)

// ---------------- fp32 -> bf16 convert (x and W merged) ----------------
__global__ __launch_bounds__(256) void cvt_bf16_2(const float* __restrict__ sA,
                                                  unsigned short* __restrict__ dA, int nA,
                                                  const float* __restrict__ sB,
                                                  unsigned short* __restrict__ dB, int nB) {
  int i = blockIdx.x * 256 + threadIdx.x;
  const float* s;
  unsigned short* d;
  if (i < nA) {
    s = sA; d = dA;
  } else {
    i -= nA;
    if (i >= nB) return;
    s = sB; d = dB;
  }
  fl4 f = ((const fl4*)s)[i];
  us4 o;
  o[0] = f2bf(f[0]); o[1] = f2bf(f[1]); o[2] = f2bf(f[2]); o[3] = f2bf(f[3]);
  ((us4*)d)[i] = o;
}

// ---------------- transpose v: vT[b][c][t] = kqv[b*2048+t][2048+c] ----------------
__global__ __launch_bounds__(256) void transpose_v(const unsigned short* __restrict__ kqv,
                                                   unsigned short* __restrict__ vT) {
  int b = blockIdx.z;
  int t0 = blockIdx.x * 64;
  int c0 = blockIdx.y * 64;
  __shared__ unsigned short tile[64][68];
  int tid = threadIdx.x;
#pragma unroll
  for (int i = 0; i < 4; ++i) {
    int idx = i * 256 + tid;
    int r = idx >> 4;
    int c4 = (idx & 15) * 4;
    const unsigned short* src = kqv + ((size_t)(b * 2048 + t0 + r)) * 3072 + 2048 + c0 + c4;
    us4 v = *(const us4*)src;
    *(us4*)&tile[r][c4] = v;
  }
  __syncthreads();
#pragma unroll
  for (int i = 0; i < 4; ++i) {
    int idx = i * 256 + tid;
    int rc = idx >> 4;
    int t4 = (idx & 15) * 4;
    us4 v;
    v[0] = tile[t4 + 0][rc]; v[1] = tile[t4 + 1][rc];
    v[2] = tile[t4 + 2][rc]; v[3] = tile[t4 + 3][rc];
    unsigned short* dst = vT + ((size_t)(b * 1024 + c0 + rc)) * 2048 + t0 + t4;
    *(us4*)dst = v;
  }
}

// ---------------- g0: 256x384 BK=32 8-phase GEMM, 256 blocks = 1/CU ----------
// Staged/block = (256+384)*1024*2B = 1.31MB (vs 2.1MB/CU at 128x384 = the
// measured DMA-rate limit). LDS 80KB: 2 bufs x (A 16KB | B 24KB). 8 waves
// (2M x 4N): wave = 128 rows x 96 cols, acc[8][6]. 5 DMA ops/K-tile (A2+B3).
// Phases per tile: ph1 rd A0-3+B0-2, stg A(t+1)->buf1; ph2 rd B3-5;
// ph3 rd A4-7, stg B(t+2)->buf0 (B free after ph2 lgkm0+bar); ph4 gate
// vmcnt(3) [drain B(t+1)+A(t+1), leave B(t+2)]; ph5-8 mirror. XCD swizzle
// gives each XCD one B panel (L2-hot).
__global__ __launch_bounds__(512, 2) void gemm_g0(
    const unsigned short* __restrict__ A, const unsigned short* __restrict__ B,
    unsigned short* __restrict__ C, const float* __restrict__ bias) {
  const int flat = blockIdx.x;
  const int swz = (flat & 7) * 32 + (flat >> 3);   // XCD-contiguous remap
  const int bx = swz >> 5;                         // 0..7 : one B panel per XCD
  const int by = swz & 31;                         // 0..31
  const int rowBase = by * 256, colBase = bx * 384;
  const int lda = 1024, ldc = 3072, nk = 32;

  __shared__ __align__(16) unsigned char lds[81920];  // 2 x (A 16KB | B 24KB)
  const int tid = threadIdx.x;
  const int lane = tid & 63, wid = tid >> 6;
  const int wr = wid >> 2, wc = wid & 3;
  const int l15 = lane & 15, l4 = lane >> 4;

  f32x4 acc[8][6] = {};
  bf16x8 af0[4], af1[4], bf[6];

  const unsigned short* Ab = A + (size_t)rowBase * lda;
  const unsigned short* Bb = B + (size_t)colBase * lda;
  unsigned aoff[2], boff[3], aldso[2], bldso[3];
#pragma unroll
  for (int i = 0; i < 3; ++i) {
    int off = i * 8192 + tid * 16;
    int r = off >> 6;                              // 64B rows (32 bf16)
    int sb = ((off >> 4) & 3) ^ ((r >> 1) & 3);    // pre-swizzled source block
    if (i < 2) { aoff[i] = (unsigned)(r * lda + sb * 8); aldso[i] = (unsigned)off; }
    boff[i] = (unsigned)(r * lda + sb * 8);
    bldso[i] = (unsigned)off;
  }

  auto STA = [&](int buf, int op, int koff) {
    async16(Ab + (size_t)(aoff[op] + (unsigned)koff), lds + buf * 40960 + aldso[op]);
  };
  auto STB = [&](int buf, int op, int koff) {
    async16(Bb + (size_t)(boff[op] + (unsigned)koff),
            lds + buf * 40960 + 16384 + bldso[op]);
  };
  auto RA = [&](int buf, int m) -> bf16x8 {
    int row = wr * 128 + m * 16 + l15;
    return *(const bf16x8*)(lds + buf * 40960 + row * 64 +
                            (((l4 ^ (row >> 1)) & 3) * 16));
  };
  auto RB = [&](int buf, int n) -> bf16x8 {
    int row = wc * 96 + n * 16 + l15;
    return *(const bf16x8*)(lds + buf * 40960 + 16384 + row * 64 +
                            (((l4 ^ (row >> 1)) & 3) * 16));
  };

#define RD_A03(BUF) _Pragma("unroll") for (int mi = 0; mi < 4; ++mi) af0[mi] = RA((BUF), mi)
#define RD_A47(BUF) _Pragma("unroll") for (int mi = 0; mi < 4; ++mi) af1[mi] = RA((BUF), 4 + mi)
#define RD_B02(BUF) _Pragma("unroll") for (int nj = 0; nj < 3; ++nj) bf[nj] = RB((BUF), nj)
#define RD_B35(BUF) _Pragma("unroll") for (int nj = 0; nj < 3; ++nj) bf[3 + nj] = RB((BUF), 3 + nj)

#define MQ(MB, NB, AF)                                                         \
  _Pragma("unroll") for (int mi = 0; mi < 4; ++mi)                             \
  _Pragma("unroll") for (int nj = 0; nj < 3; ++nj)                             \
      acc[(MB) + mi][(NB) + nj] = __builtin_amdgcn_mfma_f32_16x16x32_bf16(     \
          AF[mi], bf[(NB) + nj], acc[(MB) + mi][(NB) + nj], 0, 0, 0)

#define PHASE(RDS, STG, GATE, MB, NB, AF)                                      \
  do {                                                                         \
    RDS;                                                                       \
    STG;                                                                       \
    BARM();                                                                    \
    LGKM0();                                                                   \
    SCHEDB();                                                                  \
    __builtin_amdgcn_s_setprio(1);                                             \
    MQ(MB, NB, AF);                                                            \
    __builtin_amdgcn_s_setprio(0);                                             \
    GATE;                                                                      \
    BARM();                                                                    \
  } while (0)

  // prologue: A(0),B(0)->buf0 (5 ops), B(1)->buf1 (3 ops); gate leaves B(1)
  STA(0, 0, 0); STA(0, 1, 0);
#pragma unroll
  for (int i = 0; i < 3; ++i) STB(0, i, 0);
#pragma unroll
  for (int i = 0; i < 3; ++i) STB(1, i, 32);
  VMCNT3();
  BARM();

  for (int it = 0; it < 16; ++it) {
    int t = it * 2;
    int kA1 = (t + 1) * 32;
    int k2 = (t + 2 < nk - 1 ? t + 2 : nk - 1) * 32;
    int k3 = (t + 3 < nk - 1 ? t + 3 : nk - 1) * 32;
    // tile t from buf0
    PHASE({ RD_A03(0); RD_B02(0); }, { STA(1, 0, kA1); STA(1, 1, kA1); },
          (void)0, 0, 0, af0);
    PHASE({ RD_B35(0); }, (void)0, (void)0, 0, 3, af0);
    PHASE({ RD_A47(0); }, { STB(0, 0, k2); STB(0, 1, k2); STB(0, 2, k2); },
          (void)0, 4, 3, af1);
    PHASE({}, (void)0, VMCNT3(), 4, 0, af1);
    // tile t+1 from buf1
    PHASE({ RD_A03(1); RD_B02(1); }, { STA(0, 0, k2); STA(0, 1, k2); },
          (void)0, 0, 0, af0);
    PHASE({ RD_B35(1); }, (void)0, (void)0, 0, 3, af0);
    PHASE({ RD_A47(1); }, { STB(1, 0, k3); STB(1, 1, k3); STB(1, 2, k3); },
          (void)0, 4, 3, af1);
    PHASE({}, (void)0, VMCNT3(), 4, 0, af1);
  }
#undef PHASE
#undef MQ
#undef RD_A03
#undef RD_A47
#undef RD_B02
#undef RD_B35

  const int cr = l4 * 4;
#pragma unroll
  for (int n = 0; n < 6; ++n) {
    int col = colBase + wc * 96 + n * 16 + l15;
    float bv = bias[col];
#pragma unroll
    for (int m = 0; m < 8; ++m) {
      int row = rowBase + wr * 128 + m * 16 + cr;
#pragma unroll
      for (int i = 0; i < 4; ++i)
        C[(size_t)(row + i) * ldc + col] = f2bf(acc[m][n][i] + bv);
    }
  }
}

// ---------------- g1: 256x256 8-phase GEMM, S = (k@q^T)*scale, causal skip ----
__global__ __launch_bounds__(512, 2) void gemm_s(
    const unsigned short* __restrict__ A, int lda, long long sA,
    const unsigned short* __restrict__ B, int ldb, long long sB,
    unsigned short* __restrict__ C, int ldc, long long sC,
    float scale, int K) {
  int bx = blockIdx.x, by = blockIdx.y;
  const int bz = blockIdx.z;
  if (bx > by) return;
  A += (size_t)bz * sA;
  B += (size_t)bz * sB;
  const int rowBase = by * 256;
  const int colBase = bx * 256;
  const int nk = K / 64;

  __shared__ __align__(16) unsigned char lds[131072];
  const int tid = threadIdx.x;
  const int lane = tid & 63;
  const int wid = tid >> 6;
  const int wr = wid >> 2;
  const int wc = wid & 3;
  const int l15 = lane & 15, l4 = lane >> 4, l7 = lane & 7;

  f32x4 acc[8][4] = {};
  bf16x8 af0[4][2], af1[4][2], bf0[2][2], bf1[2][2];

  const unsigned short* Ab = A + (size_t)rowBase * lda;
  const unsigned short* Bb = B + (size_t)colBase * ldb;
  unsigned loff[2][2];
  unsigned lldso[2];
#pragma unroll
  for (int i = 0; i < 2; ++i) {
    int off = (i * 512 + tid) * 16;
    int r = off >> 7;
    int sb = ((off >> 4) & 7) ^ (r & 7);
    lldso[i] = (unsigned)off;
#pragma unroll
    for (int hh = 0; hh < 2; ++hh)
      loff[hh][i] = (unsigned)((hh * 128 + r) * lda + sb * 8);
  }

  auto STAGE = [&](int bufc, int isB, int half, const unsigned short* Gb, int koff) {
#pragma unroll
    for (int i = 0; i < 2; ++i)
      async16(Gb + (size_t)(loff[half][i] + (unsigned)koff),
              lds + bufc * 65536 + isB * 32768 + half * 16384 + lldso[i]);
  };
  auto RDA = [&](int bufc, int m, int kk) -> bf16x8 {
    int row = m * 16 + l15;
    int blk = (kk * 4 + l4) ^ l7;
    return *(const bf16x8*)(lds + bufc * 65536 + wr * 16384 + row * 128 + blk * 16);
  };
  auto RDB = [&](int bufc, int n, int kk) -> bf16x8 {
    int row = (wc & 1) * 64 + n * 16 + l15;
    int blk = (kk * 4 + l4) ^ l7;
    return *(const bf16x8*)(lds + bufc * 65536 + 32768 + (wc >> 1) * 16384 +
                            row * 128 + blk * 16);
  };

#define RDA8(dst, BUF, Q)                                                      \
  _Pragma("unroll") for (int mi = 0; mi < 4; ++mi)                             \
  _Pragma("unroll") for (int kk = 0; kk < 2; ++kk)                             \
      dst[mi][kk] = RDA((BUF), (Q) * 4 + mi, kk)
#define RDB4(dst, BUF, NB)                                                     \
  _Pragma("unroll") for (int nj = 0; nj < 2; ++nj)                             \
  _Pragma("unroll") for (int kk = 0; kk < 2; ++kk)                             \
      dst[nj][kk] = RDB((BUF), (NB) + nj, kk)

#define MFMAQ(MB, NB, AF, BF)                                                  \
  _Pragma("unroll") for (int kk = 0; kk < 2; ++kk)                             \
  _Pragma("unroll") for (int mi = 0; mi < 4; ++mi)                             \
  _Pragma("unroll") for (int nj = 0; nj < 2; ++nj)                             \
      acc[(MB) + mi][(NB) + nj] = __builtin_amdgcn_mfma_f32_16x16x32_bf16(     \
          AF[mi][kk], BF[nj][kk], acc[(MB) + mi][(NB) + nj], 0, 0, 0)

#define PH(RDS, STG, HINT, GATE, MB, NB, AF, BF)                               \
  do {                                                                         \
    RDS;                                                                       \
    STG;                                                                       \
    HINT;                                                                      \
    BARM();                                                                    \
    LGKM0();                                                                   \
    SCHEDB();                                                                  \
    __builtin_amdgcn_s_setprio(1);                                             \
    MFMAQ(MB, NB, AF, BF);                                                     \
    __builtin_amdgcn_s_setprio(0);                                             \
    GATE;                                                                      \
    BARM();                                                                    \
  } while (0)

  STAGE(0, 0, 0, Ab, 0);
  STAGE(0, 0, 1, Ab, 0);
  STAGE(0, 1, 0, Bb, 0);
  STAGE(0, 1, 1, Bb, 0);
  STAGE(1, 1, 0, Bb, 64);
  STAGE(1, 1, 1, Bb, 64);
  VMCNT4();
  BARM();

  const int nt2 = nk >> 1;
  for (int it = 0; it < nt2; ++it) {
    int t = it * 2;
    int kA1 = (t + 1) * 64;
    int k2 = (t + 2 < nk - 1 ? t + 2 : nk - 1) * 64;
    int k3 = (t + 3 < nk - 1 ? t + 3 : nk - 1) * 64;
    PH({ RDA8(af0, 0, 0); RDB4(bf0, 0, 0); }, STAGE(1, 0, 0, Ab, kA1), LGKM8(),
       (void)0, 0, 0, af0, bf0);
    PH({ RDB4(bf1, 0, 2); }, STAGE(1, 0, 1, Ab, kA1), (void)0,
       (void)0, 0, 2, af0, bf1);
    PH({ RDA8(af1, 0, 1); }, STAGE(0, 1, 0, Bb, k2), (void)0,
       (void)0, 4, 2, af1, bf1);
    PH({}, STAGE(0, 1, 1, Bb, k2), (void)0,
       VMCNT4(), 4, 0, af1, bf0);
    PH({ RDA8(af0, 1, 0); RDB4(bf0, 1, 0); }, STAGE(0, 0, 0, Ab, k2), LGKM8(),
       (void)0, 0, 0, af0, bf0);
    PH({ RDB4(bf1, 1, 2); }, STAGE(0, 0, 1, Ab, k2), (void)0,
       (void)0, 0, 2, af0, bf1);
    PH({ RDA8(af1, 1, 1); }, STAGE(1, 1, 0, Bb, k3), (void)0,
       (void)0, 4, 2, af1, bf1);
    PH({}, STAGE(1, 1, 1, Bb, k3), (void)0,
       VMCNT4(), 4, 0, af1, bf0);
  }
#undef PH
#undef MFMAQ
#undef RDA8
#undef RDB4

  const int cr = l4 * 4;
  unsigned short* Cb = C + (size_t)bz * sC;
#pragma unroll
  for (int n = 0; n < 4; ++n) {
    int col = colBase + wc * 64 + n * 16 + l15;
#pragma unroll
    for (int m = 0; m < 8; ++m) {
      int row = rowBase + wr * 128 + m * 16 + cr;
#pragma unroll
      for (int i = 0; i < 4; ++i)
        Cb[(size_t)(row + i) * ldc + col] = f2bf(acc[m][n][i] * scale);
    }
  }
}

// ---------------- g2: two-chain pv — uniform 34 K-tiles per block -------------
__global__ __launch_bounds__(256, 2) void gemm_pv2(
    const unsigned short* __restrict__ S, const unsigned short* __restrict__ V,
    float* __restrict__ O) {
  const int f = blockIdx.x;
  const int bx = f & 7;
  const int p = (f >> 3) & 7;
  const int bz = f >> 6;
  const int byH = 15 - p;
  const int nkL = 2 * (p + 1);
  const int nkH = 32 - 2 * p;
  const unsigned short* base = S + (size_t)bz * 2048 * 2048;
  const unsigned short* AH = base + (size_t)(byH * 128) * 2048;
  const unsigned short* AL = base + (size_t)(p * 128) * 2048;
  const unsigned short* Bb = V + (size_t)bz * 1024 * 2048 + (size_t)(bx * 128) * 2048;
  float* Ob = O + (size_t)bz * 2048 * 1024;

  __shared__ __align__(16) unsigned char lds[65536];
  const int tid = threadIdx.x;
  const int lane = tid & 63, wid = tid >> 6;
  const int wr = (wid >> 1) * 64, wc = (wid & 1) * 64;
  const int l15 = lane & 15, l4 = lane >> 4, l7 = lane & 7;

  f32x4 accH[4][4] = {}, accL[4][4] = {};

  unsigned goff[4], ldso[4];
#pragma unroll
  for (int ii = 0; ii < 4; ++ii) {
    int off = (ii * 256 + tid) * 16;
    int rr = off >> 7;
    int sb = ((off >> 4) & 7) ^ (rr & 7);
    goff[ii] = (unsigned)(rr * 2048 + sb * 8);
    ldso[ii] = (unsigned)off;
  }

  auto ST = [&](int buf, const unsigned short* Ap, unsigned kof) {
#pragma unroll
    for (int ii = 0; ii < 4; ++ii) {
      async16(Ap + (size_t)(goff[ii] + kof), lds + buf * 32768 + ldso[ii]);
      async16(Bb + (size_t)(goff[ii] + kof), lds + buf * 32768 + 16384 + ldso[ii]);
    }
  };
  auto ITEM = [&](int i, const unsigned short*& P, unsigned& kf) {
    if (i < 2 * nkL) {
      P = (i & 1) ? AL : AH;
      kf = (unsigned)((i >> 1) * 64);
    } else {
      P = AH;
      kf = (unsigned)((i - nkL) * 64);
    }
  };

#define PVSTEP(BUF, ACC, NITEM)                                                \
  do {                                                                         \
    const unsigned short* nP;                                                  \
    unsigned nK;                                                               \
    ITEM((NITEM) < 33 ? (NITEM) : 33, nP, nK);                                 \
    VMCNT8();                                                                  \
    BARM();                                                                    \
    bf16x8 af[4][2], bfr[4][2];                                                \
    _Pragma("unroll") for (int m = 0; m < 4; ++m) {                            \
      int row = wr + m * 16 + l15;                                             \
      _Pragma("unroll") for (int kk = 0; kk < 2; ++kk)                         \
        af[m][kk] = *(const bf16x8*)(lds + (BUF) * 32768 + row * 128 +         \
                                     (((kk * 4 + l4) ^ l7) * 16));             \
    }                                                                          \
    _Pragma("unroll") for (int n = 0; n < 4; ++n) {                            \
      int row = wc + n * 16 + l15;                                             \
      _Pragma("unroll") for (int kk = 0; kk < 2; ++kk)                         \
        bfr[n][kk] = *(const bf16x8*)(lds + (BUF) * 32768 + 16384 + row * 128 +\
                                      (((kk * 4 + l4) ^ l7) * 16));            \
    }                                                                          \
    LGKM0();                                                                   \
    BARM();                                                                    \
    ST((BUF), nP, nK);                                                         \
    SCHEDB();                                                                  \
    __builtin_amdgcn_s_setprio(1);                                             \
    _Pragma("unroll") for (int kk = 0; kk < 2; ++kk)                           \
    _Pragma("unroll") for (int m = 0; m < 4; ++m)                              \
    _Pragma("unroll") for (int n = 0; n < 4; ++n)                              \
      ACC[m][n] = __builtin_amdgcn_mfma_f32_16x16x32_bf16(af[m][kk], bfr[n][kk],\
                                                          ACC[m][n], 0, 0, 0); \
    __builtin_amdgcn_s_setprio(0);                                             \
  } while (0)

  ST(0, AH, 0);
  {
    const unsigned short* P; unsigned kf;
    ITEM(1, P, kf);
    ST(1, P, kf);
  }

  for (int t = 0; t < nkL; ++t) {
    PVSTEP(0, accH, 2 * t + 2);
    PVSTEP(1, accL, 2 * t + 3);
  }
  for (int u = nkL; u < nkH; u += 2) {
    PVSTEP(0, accH, u + nkL + 2);
    PVSTEP(1, accH, u + nkL + 3);
  }
#undef PVSTEP

  const int cr = l4 * 4;
#pragma unroll
  for (int n = 0; n < 4; ++n) {
    int col = bx * 128 + wc + n * 16 + l15;
#pragma unroll
    for (int m = 0; m < 4; ++m) {
      int rH = byH * 128 + wr + m * 16 + cr;
      int rL = p * 128 + wr + m * 16 + cr;
#pragma unroll
      for (int i = 0; i < 4; ++i) {
        Ob[(size_t)(rH + i) * 1024 + col] = accH[m][n][i];
        Ob[(size_t)(rL + i) * 1024 + col] = accL[m][n][i];
      }
    }
  }
}

// ---------------- causal softmax over S rows (in place, bf16) ----------------
__global__ __launch_bounds__(256) void softmax_causal(unsigned short* __restrict__ S) {
  const int T = 2048;
  int t = blockIdx.x, b = blockIdx.y;
  unsigned short* row = S + ((size_t)b * T + t) * T;
  const int nv = t + 1;
  const int bound = ((t >> 7) + 1) << 7;
  int tid = threadIdx.x;
  int lane = tid & 63, wid = tid >> 6;
  int s0 = tid * 8;
  us8 raw = {};
  if (s0 < nv) raw = *(const us8*)(row + s0);
  float v[8];
  float m = -3.0e38f;
#pragma unroll
  for (int j = 0; j < 8; ++j) {
    v[j] = bf2f(raw[j]);
    if (s0 + j < nv) m = fmaxf(m, v[j]);
  }
#pragma unroll
  for (int o = 32; o > 0; o >>= 1) m = fmaxf(m, __shfl_xor(m, o, 64));
  __shared__ float red[4];
  if (lane == 0) red[wid] = m;
  __syncthreads();
  m = fmaxf(fmaxf(red[0], red[1]), fmaxf(red[2], red[3]));
  __syncthreads();
  float sum = 0.f;
#pragma unroll
  for (int j = 0; j < 8; ++j) {
    float e = (s0 + j < nv) ? exp2f(v[j] - m) : 0.f;
    v[j] = e;
    sum += e;
  }
#pragma unroll
  for (int o = 32; o > 0; o >>= 1) sum += __shfl_xor(sum, o, 64);
  if (lane == 0) red[wid] = sum;
  __syncthreads();
  sum = red[0] + red[1] + red[2] + red[3];
  float inv = 1.0f / sum;
  if (s0 < bound) {
    us8 outv;
#pragma unroll
    for (int j = 0; j < 8; ++j) outv[j] = f2bf(v[j] * inv);
    *(us8*)(row + s0) = outv;
  }
}

extern "C" void kernel_launch(void* const* d_in, const int* in_sizes, int n_in,
                              void* d_out, int out_size, void* d_ws, size_t ws_size,
                              hipStream_t stream) {
  const float* x = (const float*)d_in[0];      // [4,2048,1024]
  const float* W = (const float*)d_in[1];      // [3072,1024]
  const float* bias = (const float*)d_in[2];   // [3072]
  float* out = (float*)d_out;                  // [4,2048,1024]

  char* ws = (char*)d_ws;
  if (ws_size < 106954752u) return;
  unsigned short* xbf = (unsigned short*)(ws);
  unsigned short* vT = xbf;  // alias: xbf dead after gemm_g0
  unsigned short* wbf = (unsigned short*)(ws + 16777216);
  unsigned short* kqv = (unsigned short*)(ws + 23068672);
  unsigned short* S = (unsigned short*)(ws + 73400320);

  const float kSoftmaxScale = 1.4426950408889634f / 32.0f;  // log2(e)/sqrt(1024)

  cvt_bf16_2<<<11264, 256, 0, stream>>>(x, xbf, 2097152, W, wbf, 786432);

  // kqv = x @ W^T + b : 256x384 tiles, 32x8 = 256 blocks = exactly 1/CU
  gemm_g0<<<dim3(256, 1, 1), 512, 0, stream>>>(xbf, wbf, kqv, bias);

  transpose_v<<<dim3(32, 16, 4), 256, 0, stream>>>(kqv, vT);

  // S = (k @ q^T) * log2e/32 (bf16), causal blocks skipped
  gemm_s<<<dim3(8, 8, 4), 512, 0, stream>>>(
      kqv, 3072, 2048LL * 3072, kqv + 1024, 3072, 2048LL * 3072,
      S, 2048, 2048LL * 2048, kSoftmaxScale, 1024);

  softmax_causal<<<dim3(2048, 4), 256, 0, stream>>>(S);

  // out = P @ vT^T (fp32): two-chain blocks, uniform 34 K-tiles, 256 = 1/CU
  gemm_pv2<<<dim3(256, 1, 1), 256, 0, stream>>>(S, vT, out);
}

// Round 15
// 171.262 us; speedup vs baseline: 1.0371x; 1.0371x over previous
//
#include <hip/hip_runtime.h>

typedef __bf16 bf16x8 __attribute__((ext_vector_type(8)));
typedef float f32x4 __attribute__((ext_vector_type(4)));
typedef float fl4 __attribute__((ext_vector_type(4)));
typedef unsigned short us4 __attribute__((ext_vector_type(4)));
typedef unsigned short us8 __attribute__((ext_vector_type(8)));

__device__ __forceinline__ unsigned short f2bf(float f) {
  unsigned u = __builtin_bit_cast(unsigned, f);
  u += 0x7fffu + ((u >> 16) & 1u);
  return (unsigned short)(u >> 16);
}
__device__ __forceinline__ float bf2f(unsigned short h) {
  unsigned u = ((unsigned)h) << 16;
  return __builtin_bit_cast(float, u);
}

__device__ __forceinline__ void async16(const void* g, void* l) {
  __builtin_amdgcn_global_load_lds(
      (const __attribute__((address_space(1))) unsigned int*)g,
      (__attribute__((address_space(3))) unsigned int*)l, 16, 0, 0);
}

#define BARM() asm volatile("s_barrier" ::: "memory")
#define VMCNT4() asm volatile("s_waitcnt vmcnt(4)" ::: "memory")
#define VMCNT6() asm volatile("s_waitcnt vmcnt(6)" ::: "memory")
#define LGKM0() asm volatile("s_waitcnt lgkmcnt(0)" ::: "memory")
#define LGKM8() asm volatile("s_waitcnt lgkmcnt(8)" ::: "memory")
#define SCHEDB() __builtin_amdgcn_sched_barrier(0)

// ---------------- fp32 -> bf16 convert (x and W merged) ----------------
__global__ __launch_bounds__(256) void cvt_bf16_2(const float* __restrict__ sA,
                                                  unsigned short* __restrict__ dA, int nA,
                                                  const float* __restrict__ sB,
                                                  unsigned short* __restrict__ dB, int nB) {
  int i = blockIdx.x * 256 + threadIdx.x;
  const float* s;
  unsigned short* d;
  if (i < nA) {
    s = sA; d = dA;
  } else {
    i -= nA;
    if (i >= nB) return;
    s = sB; d = dB;
  }
  fl4 f = ((const fl4*)s)[i];
  us4 o;
  o[0] = f2bf(f[0]); o[1] = f2bf(f[1]); o[2] = f2bf(f[2]); o[3] = f2bf(f[3]);
  ((us4*)d)[i] = o;
}

// ---------------- transpose v: vT[b][c][t] = kqv[b*2048+t][2048+c] ----------------
__global__ __launch_bounds__(256) void transpose_v(const unsigned short* __restrict__ kqv,
                                                   unsigned short* __restrict__ vT) {
  int b = blockIdx.z;
  int t0 = blockIdx.x * 64;
  int c0 = blockIdx.y * 64;
  __shared__ unsigned short tile[64][68];
  int tid = threadIdx.x;
#pragma unroll
  for (int i = 0; i < 4; ++i) {
    int idx = i * 256 + tid;
    int r = idx >> 4;
    int c4 = (idx & 15) * 4;
    const unsigned short* src = kqv + ((size_t)(b * 2048 + t0 + r)) * 3072 + 2048 + c0 + c4;
    us4 v = *(const us4*)src;
    *(us4*)&tile[r][c4] = v;
  }
  __syncthreads();
#pragma unroll
  for (int i = 0; i < 4; ++i) {
    int idx = i * 256 + tid;
    int rc = idx >> 4;
    int t4 = (idx & 15) * 4;
    us4 v;
    v[0] = tile[t4 + 0][rc]; v[1] = tile[t4 + 1][rc];
    v[2] = tile[t4 + 2][rc]; v[3] = tile[t4 + 3][rc];
    unsigned short* dst = vT + ((size_t)(b * 1024 + c0 + rc)) * 2048 + t0 + t4;
    *(us4*)dst = v;
  }
}

// ---------------- g0: 128x384 8-phase GEMM, 512 blocks = 2 exact rounds -------
// (r13 proven version: 62.6us, DMA-staging-rate-limited at ~14 B/cyc/CU)
__global__ __launch_bounds__(512, 2) void gemm_g0(
    const unsigned short* __restrict__ A, const unsigned short* __restrict__ B,
    unsigned short* __restrict__ C, const float* __restrict__ bias) {
  const int flat = blockIdx.x;
  const int swz = (flat & 7) * 64 + (flat >> 3);   // XCD-contiguous remap
  const int bx = swz & 7;
  const int by = swz >> 3;
  const int rowBase = by * 128, colBase = bx * 384;
  const int lda = 1024, ldc = 3072, nk = 16;

  __shared__ __align__(16) unsigned char lds[131072];
  const int tid = threadIdx.x;
  const int lane = tid & 63, wid = tid >> 6;
  const int wr = wid >> 2, wc = wid & 3;
  const int l15 = lane & 15, l4 = lane >> 4, l7 = lane & 7;

  f32x4 acc[4][6] = {};
  bf16x8 af01[2][2], af23[2][2], bf[6][2];

  const unsigned short* Ab = A + (size_t)rowBase * lda;
  const unsigned short* Bb = B + (size_t)colBase * lda;
  unsigned aoff[2], boff[6], aldso[2], bldso[6];
#pragma unroll
  for (int i = 0; i < 6; ++i) {
    int off = i * 8192 + tid * 16;
    int r = off >> 7;
    int sb = ((off >> 4) & 7) ^ (r & 7);
    if (i < 2) { aoff[i] = (unsigned)(r * lda + sb * 8); aldso[i] = (unsigned)off; }
    boff[i] = (unsigned)(r * lda + sb * 8);
    bldso[i] = (unsigned)off;
  }

  auto STA = [&](int bufc, int op, int koff) {
    async16(Ab + (size_t)(aoff[op] + (unsigned)koff), lds + bufc * 65536 + aldso[op]);
  };
  auto STB = [&](int bufc, int op, int koff) {
    async16(Bb + (size_t)(boff[op] + (unsigned)koff),
            lds + bufc * 65536 + 16384 + bldso[op]);
  };
  auto RA = [&](int bufc, int m, int kk) -> bf16x8 {
    int row = wr * 64 + m * 16 + l15;
    int blk = (kk * 4 + l4) ^ l7;
    return *(const bf16x8*)(lds + bufc * 65536 + row * 128 + blk * 16);
  };
  auto RB = [&](int bufc, int n, int kk) -> bf16x8 {
    int row = wc * 96 + n * 16 + l15;
    int blk = (kk * 4 + l4) ^ l7;
    return *(const bf16x8*)(lds + bufc * 65536 + 16384 + row * 128 + blk * 16);
  };

#define RD_A01(BUF)                                                            \
  _Pragma("unroll") for (int mi = 0; mi < 2; ++mi)                             \
  _Pragma("unroll") for (int kk = 0; kk < 2; ++kk) af01[mi][kk] = RA((BUF), mi, kk)
#define RD_A23(BUF)                                                            \
  _Pragma("unroll") for (int mi = 0; mi < 2; ++mi)                             \
  _Pragma("unroll") for (int kk = 0; kk < 2; ++kk) af23[mi][kk] = RA((BUF), 2 + mi, kk)
#define RD_B(BUF, N0)                                                          \
  _Pragma("unroll") for (int nj = 0; nj < 3; ++nj)                             \
  _Pragma("unroll") for (int kk = 0; kk < 2; ++kk) bf[(N0) + nj][kk] = RB((BUF), (N0) + nj, kk)

#define MQ(MB, NB, AF)                                                         \
  _Pragma("unroll") for (int kk = 0; kk < 2; ++kk)                             \
  _Pragma("unroll") for (int mi = 0; mi < 2; ++mi)                             \
  _Pragma("unroll") for (int nj = 0; nj < 3; ++nj)                             \
      acc[(MB) + mi][(NB) + nj] = __builtin_amdgcn_mfma_f32_16x16x32_bf16(     \
          AF[mi][kk], bf[(NB) + nj][kk], acc[(MB) + mi][(NB) + nj], 0, 0, 0)

#define PHASE(RDS, STG, GATE, MB, NB, AF)                                      \
  do {                                                                         \
    RDS;                                                                       \
    STG;                                                                       \
    BARM();                                                                    \
    LGKM0();                                                                   \
    SCHEDB();                                                                  \
    __builtin_amdgcn_s_setprio(1);                                             \
    MQ(MB, NB, AF);                                                            \
    __builtin_amdgcn_s_setprio(0);                                             \
    GATE;                                                                      \
    BARM();                                                                    \
  } while (0)

  STA(0, 0, 0); STA(0, 1, 0);
#pragma unroll
  for (int i = 0; i < 6; ++i) STB(0, i, 0);
#pragma unroll
  for (int i = 0; i < 6; ++i) STB(1, i, 64);
  VMCNT6();
  BARM();

  for (int it = 0; it < 8; ++it) {
    int t = it * 2;
    int kA1 = (t + 1) * 64;
    int k2 = (t + 2 < nk - 1 ? t + 2 : nk - 1) * 64;
    int k3 = (t + 3 < nk - 1 ? t + 3 : nk - 1) * 64;
    PHASE({ RD_A01(0); RD_B(0, 0); }, { STA(1, 0, kA1); STA(1, 1, kA1); },
          (void)0, 0, 0, af01);
    PHASE({ RD_A23(0); RD_B(0, 3); }, (void)0, (void)0, 0, 3, af01);
    PHASE({}, { STB(0, 0, k2); STB(0, 1, k2); STB(0, 2, k2); },
          (void)0, 2, 3, af23);
    PHASE({}, { STB(0, 3, k2); STB(0, 4, k2); STB(0, 5, k2); },
          VMCNT6(), 2, 0, af23);
    PHASE({ RD_A01(1); RD_B(1, 0); }, { STA(0, 0, k2); STA(0, 1, k2); },
          (void)0, 0, 0, af01);
    PHASE({ RD_A23(1); RD_B(1, 3); }, (void)0, (void)0, 0, 3, af01);
    PHASE({}, { STB(1, 0, k3); STB(1, 1, k3); STB(1, 2, k3); },
          (void)0, 2, 3, af23);
    PHASE({}, { STB(1, 3, k3); STB(1, 4, k3); STB(1, 5, k3); },
          VMCNT6(), 2, 0, af23);
  }
#undef PHASE
#undef MQ
#undef RD_A01
#undef RD_A23
#undef RD_B

  const int cr = l4 * 4;
#pragma unroll
  for (int n = 0; n < 6; ++n) {
    int col = colBase + wc * 96 + n * 16 + l15;
    float bv = bias[col];
#pragma unroll
    for (int m = 0; m < 4; ++m) {
      int row = rowBase + wr * 64 + m * 16 + cr;
#pragma unroll
      for (int i = 0; i < 4; ++i)
        C[(size_t)(row + i) * ldc + col] = f2bf(acc[m][n][i] + bv);
    }
  }
}

// ---------------- g1: 256x256 8-phase GEMM, S = (k@q^T)*scale, causal skip ----
__global__ __launch_bounds__(512, 2) void gemm_s(
    const unsigned short* __restrict__ A, int lda, long long sA,
    const unsigned short* __restrict__ B, int ldb, long long sB,
    unsigned short* __restrict__ C, int ldc, long long sC,
    float scale, int K) {
  int bx = blockIdx.x, by = blockIdx.y;
  const int bz = blockIdx.z;
  if (bx > by) return;
  A += (size_t)bz * sA;
  B += (size_t)bz * sB;
  const int rowBase = by * 256;
  const int colBase = bx * 256;
  const int nk = K / 64;

  __shared__ __align__(16) unsigned char lds[131072];
  const int tid = threadIdx.x;
  const int lane = tid & 63;
  const int wid = tid >> 6;
  const int wr = wid >> 2;
  const int wc = wid & 3;
  const int l15 = lane & 15, l4 = lane >> 4, l7 = lane & 7;

  f32x4 acc[8][4] = {};
  bf16x8 af0[4][2], af1[4][2], bf0[2][2], bf1[2][2];

  const unsigned short* Ab = A + (size_t)rowBase * lda;
  const unsigned short* Bb = B + (size_t)colBase * ldb;
  unsigned loff[2][2];
  unsigned lldso[2];
#pragma unroll
  for (int i = 0; i < 2; ++i) {
    int off = (i * 512 + tid) * 16;
    int r = off >> 7;
    int sb = ((off >> 4) & 7) ^ (r & 7);
    lldso[i] = (unsigned)off;
#pragma unroll
    for (int hh = 0; hh < 2; ++hh)
      loff[hh][i] = (unsigned)((hh * 128 + r) * lda + sb * 8);
  }

  auto STAGE = [&](int bufc, int isB, int half, const unsigned short* Gb, int koff) {
#pragma unroll
    for (int i = 0; i < 2; ++i)
      async16(Gb + (size_t)(loff[half][i] + (unsigned)koff),
              lds + bufc * 65536 + isB * 32768 + half * 16384 + lldso[i]);
  };
  auto RDA = [&](int bufc, int m, int kk) -> bf16x8 {
    int row = m * 16 + l15;
    int blk = (kk * 4 + l4) ^ l7;
    return *(const bf16x8*)(lds + bufc * 65536 + wr * 16384 + row * 128 + blk * 16);
  };
  auto RDB = [&](int bufc, int n, int kk) -> bf16x8 {
    int row = (wc & 1) * 64 + n * 16 + l15;
    int blk = (kk * 4 + l4) ^ l7;
    return *(const bf16x8*)(lds + bufc * 65536 + 32768 + (wc >> 1) * 16384 +
                            row * 128 + blk * 16);
  };

#define RDA8(dst, BUF, Q)                                                      \
  _Pragma("unroll") for (int mi = 0; mi < 4; ++mi)                             \
  _Pragma("unroll") for (int kk = 0; kk < 2; ++kk)                             \
      dst[mi][kk] = RDA((BUF), (Q) * 4 + mi, kk)
#define RDB4(dst, BUF, NB)                                                     \
  _Pragma("unroll") for (int nj = 0; nj < 2; ++nj)                             \
  _Pragma("unroll") for (int kk = 0; kk < 2; ++kk)                             \
      dst[nj][kk] = RDB((BUF), (NB) + nj, kk)

#define MFMAQ(MB, NB, AF, BF)                                                  \
  _Pragma("unroll") for (int kk = 0; kk < 2; ++kk)                             \
  _Pragma("unroll") for (int mi = 0; mi < 4; ++mi)                             \
  _Pragma("unroll") for (int nj = 0; nj < 2; ++nj)                             \
      acc[(MB) + mi][(NB) + nj] = __builtin_amdgcn_mfma_f32_16x16x32_bf16(     \
          AF[mi][kk], BF[nj][kk], acc[(MB) + mi][(NB) + nj], 0, 0, 0)

#define PH(RDS, STG, HINT, GATE, MB, NB, AF, BF)                               \
  do {                                                                         \
    RDS;                                                                       \
    STG;                                                                       \
    HINT;                                                                      \
    BARM();                                                                    \
    LGKM0();                                                                   \
    SCHEDB();                                                                  \
    __builtin_amdgcn_s_setprio(1);                                             \
    MFMAQ(MB, NB, AF, BF);                                                     \
    __builtin_amdgcn_s_setprio(0);                                             \
    GATE;                                                                      \
    BARM();                                                                    \
  } while (0)

  STAGE(0, 0, 0, Ab, 0);
  STAGE(0, 0, 1, Ab, 0);
  STAGE(0, 1, 0, Bb, 0);
  STAGE(0, 1, 1, Bb, 0);
  STAGE(1, 1, 0, Bb, 64);
  STAGE(1, 1, 1, Bb, 64);
  VMCNT4();
  BARM();

  const int nt2 = nk >> 1;
  for (int it = 0; it < nt2; ++it) {
    int t = it * 2;
    int kA1 = (t + 1) * 64;
    int k2 = (t + 2 < nk - 1 ? t + 2 : nk - 1) * 64;
    int k3 = (t + 3 < nk - 1 ? t + 3 : nk - 1) * 64;
    PH({ RDA8(af0, 0, 0); RDB4(bf0, 0, 0); }, STAGE(1, 0, 0, Ab, kA1), LGKM8(),
       (void)0, 0, 0, af0, bf0);
    PH({ RDB4(bf1, 0, 2); }, STAGE(1, 0, 1, Ab, kA1), (void)0,
       (void)0, 0, 2, af0, bf1);
    PH({ RDA8(af1, 0, 1); }, STAGE(0, 1, 0, Bb, k2), (void)0,
       (void)0, 4, 2, af1, bf1);
    PH({}, STAGE(0, 1, 1, Bb, k2), (void)0,
       VMCNT4(), 4, 0, af1, bf0);
    PH({ RDA8(af0, 1, 0); RDB4(bf0, 1, 0); }, STAGE(0, 0, 0, Ab, k2), LGKM8(),
       (void)0, 0, 0, af0, bf0);
    PH({ RDB4(bf1, 1, 2); }, STAGE(0, 0, 1, Ab, k2), (void)0,
       (void)0, 0, 2, af0, bf1);
    PH({ RDA8(af1, 1, 1); }, STAGE(1, 1, 0, Bb, k3), (void)0,
       (void)0, 4, 2, af1, bf1);
    PH({}, STAGE(1, 1, 1, Bb, k3), (void)0,
       VMCNT4(), 4, 0, af1, bf0);
  }
#undef PH
#undef MFMAQ
#undef RDA8
#undef RDB4

  const int cr = l4 * 4;
  unsigned short* Cb = C + (size_t)bz * sC;
#pragma unroll
  for (int n = 0; n < 4; ++n) {
    int col = colBase + wc * 64 + n * 16 + l15;
#pragma unroll
    for (int m = 0; m < 8; ++m) {
      int row = rowBase + wr * 128 + m * 16 + cr;
#pragma unroll
      for (int i = 0; i < 4; ++i)
        Cb[(size_t)(row + i) * ldc + col] = f2bf(acc[m][n][i] * scale);
    }
  }
}

// ---------------- g2: two-chain pv, 8 waves (512 thr) -------------------------
// 256 blocks = 1/CU; block owns chains by=15-p (32-2p tiles) + by=p (2p+2) =
// uniform 34 K-tiles. 8 waves (2M x 4N) so DMA issue has 2x the wave contexts
// of the r13 4-wave version (tests the waves->staging-rate hypothesis).
// 2 x 32KB double buffer; item s+1 in flight at each gate -> vmcnt(4)
// (4 DMA ops per item per thread). Stage item s+2 into the just-consumed
// buffer AFTER reads drain (lgkm0 + barrier). Tail clamps to item 33.
__global__ __launch_bounds__(512, 2) void gemm_pv2(
    const unsigned short* __restrict__ S, const unsigned short* __restrict__ V,
    float* __restrict__ O) {
  const int f = blockIdx.x;
  const int bx = f & 7;
  const int p = (f >> 3) & 7;
  const int bz = f >> 6;
  const int byH = 15 - p;
  const int nkL = 2 * (p + 1);
  const int nkH = 32 - 2 * p;
  const unsigned short* base = S + (size_t)bz * 2048 * 2048;
  const unsigned short* AH = base + (size_t)(byH * 128) * 2048;
  const unsigned short* AL = base + (size_t)(p * 128) * 2048;
  const unsigned short* Bb = V + (size_t)bz * 1024 * 2048 + (size_t)(bx * 128) * 2048;
  float* Ob = O + (size_t)bz * 2048 * 1024;

  __shared__ __align__(16) unsigned char lds[65536];  // 2 bufs x (A16K | B16K)
  const int tid = threadIdx.x;
  const int lane = tid & 63, wid = tid >> 6;
  const int wr = (wid >> 2) * 64;        // 0,64
  const int wc = (wid & 3) * 32;         // 0,32,64,96
  const int l15 = lane & 15, l4 = lane >> 4, l7 = lane & 7;

  f32x4 accH[4][2] = {}, accL[4][2] = {};

  unsigned goff[2], ldso[2];
#pragma unroll
  for (int ii = 0; ii < 2; ++ii) {
    int off = (ii * 512 + tid) * 16;
    int rr = off >> 7;
    int sb = ((off >> 4) & 7) ^ (rr & 7);
    goff[ii] = (unsigned)(rr * 2048 + sb * 8);
    ldso[ii] = (unsigned)off;
  }

  auto ST = [&](int buf, const unsigned short* Ap, unsigned kof) {
#pragma unroll
    for (int ii = 0; ii < 2; ++ii) {
      async16(Ap + (size_t)(goff[ii] + kof), lds + buf * 32768 + ldso[ii]);
      async16(Bb + (size_t)(goff[ii] + kof), lds + buf * 32768 + 16384 + ldso[ii]);
    }
  };
  auto ITEM = [&](int i, const unsigned short*& P, unsigned& kf) {
    if (i < 2 * nkL) {
      P = (i & 1) ? AL : AH;
      kf = (unsigned)((i >> 1) * 64);
    } else {
      P = AH;
      kf = (unsigned)((i - nkL) * 64);
    }
  };

#define PVSTEP(BUF, ACC, NITEM)                                                \
  do {                                                                         \
    const unsigned short* nP;                                                  \
    unsigned nK;                                                               \
    ITEM((NITEM) < 33 ? (NITEM) : 33, nP, nK);                                 \
    VMCNT4();                                                                  \
    BARM();                                                                    \
    bf16x8 af[4][2], bfr[2][2];                                                \
    _Pragma("unroll") for (int m = 0; m < 4; ++m) {                            \
      int row = wr + m * 16 + l15;                                             \
      _Pragma("unroll") for (int kk = 0; kk < 2; ++kk)                         \
        af[m][kk] = *(const bf16x8*)(lds + (BUF) * 32768 + row * 128 +         \
                                     (((kk * 4 + l4) ^ l7) * 16));             \
    }                                                                          \
    _Pragma("unroll") for (int n = 0; n < 2; ++n) {                            \
      int row = wc + n * 16 + l15;                                             \
      _Pragma("unroll") for (int kk = 0; kk < 2; ++kk)                         \
        bfr[n][kk] = *(const bf16x8*)(lds + (BUF) * 32768 + 16384 + row * 128 +\
                                      (((kk * 4 + l4) ^ l7) * 16));            \
    }                                                                          \
    LGKM0();                                                                   \
    BARM();                                                                    \
    ST((BUF), nP, nK);                                                         \
    SCHEDB();                                                                  \
    __builtin_amdgcn_s_setprio(1);                                             \
    _Pragma("unroll") for (int kk = 0; kk < 2; ++kk)                           \
    _Pragma("unroll") for (int m = 0; m < 4; ++m)                              \
    _Pragma("unroll") for (int n = 0; n < 2; ++n)                              \
      ACC[m][n] = __builtin_amdgcn_mfma_f32_16x16x32_bf16(af[m][kk], bfr[n][kk],\
                                                          ACC[m][n], 0, 0, 0); \
    __builtin_amdgcn_s_setprio(0);                                             \
  } while (0)

  // prologue: items 0 (H tile0 -> buf0) and 1 (-> buf1)
  ST(0, AH, 0);
  {
    const unsigned short* P; unsigned kf;
    ITEM(1, P, kf);
    ST(1, P, kf);
  }

  // interleaved region: steps 2t (H tile t, buf0), 2t+1 (L tile t, buf1)
  for (int t = 0; t < nkL; ++t) {
    PVSTEP(0, accH, 2 * t + 2);
    PVSTEP(1, accL, 2 * t + 3);
  }
  // solo region: remaining H tiles in buffer-alternating pairs (count even)
  for (int u = nkL; u < nkH; u += 2) {
    PVSTEP(0, accH, u + nkL + 2);
    PVSTEP(1, accH, u + nkL + 3);
  }
#undef PVSTEP

  const int cr = l4 * 4;
#pragma unroll
  for (int n = 0; n < 2; ++n) {
    int col = bx * 128 + wc + n * 16 + l15;
#pragma unroll
    for (int m = 0; m < 4; ++m) {
      int rH = byH * 128 + wr + m * 16 + cr;
      int rL = p * 128 + wr + m * 16 + cr;
#pragma unroll
      for (int i = 0; i < 4; ++i) {
        Ob[(size_t)(rH + i) * 1024 + col] = accH[m][n][i];
        Ob[(size_t)(rL + i) * 1024 + col] = accL[m][n][i];
      }
    }
  }
}

// ---------------- causal softmax over S rows (in place, bf16) ----------------
__global__ __launch_bounds__(256) void softmax_causal(unsigned short* __restrict__ S) {
  const int T = 2048;
  int t = blockIdx.x, b = blockIdx.y;
  unsigned short* row = S + ((size_t)b * T + t) * T;
  const int nv = t + 1;
  const int bound = ((t >> 7) + 1) << 7;
  int tid = threadIdx.x;
  int lane = tid & 63, wid = tid >> 6;
  int s0 = tid * 8;
  us8 raw = {};
  if (s0 < nv) raw = *(const us8*)(row + s0);
  float v[8];
  float m = -3.0e38f;
#pragma unroll
  for (int j = 0; j < 8; ++j) {
    v[j] = bf2f(raw[j]);
    if (s0 + j < nv) m = fmaxf(m, v[j]);
  }
#pragma unroll
  for (int o = 32; o > 0; o >>= 1) m = fmaxf(m, __shfl_xor(m, o, 64));
  __shared__ float red[4];
  if (lane == 0) red[wid] = m;
  __syncthreads();
  m = fmaxf(fmaxf(red[0], red[1]), fmaxf(red[2], red[3]));
  __syncthreads();
  float sum = 0.f;
#pragma unroll
  for (int j = 0; j < 8; ++j) {
    float e = (s0 + j < nv) ? exp2f(v[j] - m) : 0.f;
    v[j] = e;
    sum += e;
  }
#pragma unroll
  for (int o = 32; o > 0; o >>= 1) sum += __shfl_xor(sum, o, 64);
  if (lane == 0) red[wid] = sum;
  __syncthreads();
  sum = red[0] + red[1] + red[2] + red[3];
  float inv = 1.0f / sum;
  if (s0 < bound) {
    us8 outv;
#pragma unroll
    for (int j = 0; j < 8; ++j) outv[j] = f2bf(v[j] * inv);
    *(us8*)(row + s0) = outv;
  }
}

extern "C" void kernel_launch(void* const* d_in, const int* in_sizes, int n_in,
                              void* d_out, int out_size, void* d_ws, size_t ws_size,
                              hipStream_t stream) {
  const float* x = (const float*)d_in[0];      // [4,2048,1024]
  const float* W = (const float*)d_in[1];      // [3072,1024]
  const float* bias = (const float*)d_in[2];   // [3072]
  float* out = (float*)d_out;                  // [4,2048,1024]

  char* ws = (char*)d_ws;
  if (ws_size < 106954752u) return;
  unsigned short* xbf = (unsigned short*)(ws);
  unsigned short* vT = xbf;  // alias: xbf dead after gemm_g0
  unsigned short* wbf = (unsigned short*)(ws + 16777216);
  unsigned short* kqv = (unsigned short*)(ws + 23068672);
  unsigned short* S = (unsigned short*)(ws + 73400320);

  const float kSoftmaxScale = 1.4426950408889634f / 32.0f;  // log2(e)/sqrt(1024)

  cvt_bf16_2<<<11264, 256, 0, stream>>>(x, xbf, 2097152, W, wbf, 786432);

  // kqv = x @ W^T + b : 128x384 tiles, 8x64 = 512 blocks = 2 exact rounds
  gemm_g0<<<dim3(512, 1, 1), 512, 0, stream>>>(xbf, wbf, kqv, bias);

  transpose_v<<<dim3(32, 16, 4), 256, 0, stream>>>(kqv, vT);

  // S = (k @ q^T) * log2e/32 (bf16), causal blocks skipped
  gemm_s<<<dim3(8, 8, 4), 512, 0, stream>>>(
      kqv, 3072, 2048LL * 3072, kqv + 1024, 3072, 2048LL * 3072,
      S, 2048, 2048LL * 2048, kSoftmaxScale, 1024);

  softmax_causal<<<dim3(2048, 4), 256, 0, stream>>>(S);

  // out = P @ vT^T (fp32): two-chain blocks, 8 waves, uniform 34 K-tiles
  gemm_pv2<<<dim3(256, 1, 1), 512, 0, stream>>>(S, vT, out);
}

// Round 16
// 169.302 us; speedup vs baseline: 1.0491x; 1.0116x over previous
//
#include <hip/hip_runtime.h>

typedef __bf16 bf16x8 __attribute__((ext_vector_type(8)));
typedef float f32x4 __attribute__((ext_vector_type(4)));
typedef float fl4 __attribute__((ext_vector_type(4)));
typedef unsigned short us4 __attribute__((ext_vector_type(4)));
typedef unsigned short us8 __attribute__((ext_vector_type(8)));

__device__ __forceinline__ unsigned short f2bf(float f) {
  unsigned u = __builtin_bit_cast(unsigned, f);
  u += 0x7fffu + ((u >> 16) & 1u);
  return (unsigned short)(u >> 16);
}
__device__ __forceinline__ float bf2f(unsigned short h) {
  unsigned u = ((unsigned)h) << 16;
  return __builtin_bit_cast(float, u);
}

__device__ __forceinline__ void async16(const void* g, void* l) {
  __builtin_amdgcn_global_load_lds(
      (const __attribute__((address_space(1))) unsigned int*)g,
      (__attribute__((address_space(3))) unsigned int*)l, 16, 0, 0);
}

#define BARM() asm volatile("s_barrier" ::: "memory")
#define VMCNT3() asm volatile("s_waitcnt vmcnt(3)" ::: "memory")
#define VMCNT4() asm volatile("s_waitcnt vmcnt(4)" ::: "memory")
#define VMCNT8() asm volatile("s_waitcnt vmcnt(8)" ::: "memory")
#define LGKM0() asm volatile("s_waitcnt lgkmcnt(0)" ::: "memory")
#define LGKM8() asm volatile("s_waitcnt lgkmcnt(8)" ::: "memory")
#define SCHEDB() __builtin_amdgcn_sched_barrier(0)

// ---------------- fp32 -> bf16 convert (x and W merged) ----------------
__global__ __launch_bounds__(256) void cvt_bf16_2(const float* __restrict__ sA,
                                                  unsigned short* __restrict__ dA, int nA,
                                                  const float* __restrict__ sB,
                                                  unsigned short* __restrict__ dB, int nB) {
  int i = blockIdx.x * 256 + threadIdx.x;
  const float* s;
  unsigned short* d;
  if (i < nA) {
    s = sA; d = dA;
  } else {
    i -= nA;
    if (i >= nB) return;
    s = sB; d = dB;
  }
  fl4 f = ((const fl4*)s)[i];
  us4 o;
  o[0] = f2bf(f[0]); o[1] = f2bf(f[1]); o[2] = f2bf(f[2]); o[3] = f2bf(f[3]);
  ((us4*)d)[i] = o;
}

// ---------------- transpose v: vT[b][c][t] = kqv[b*2048+t][2048+c] ----------------
__global__ __launch_bounds__(256) void transpose_v(const unsigned short* __restrict__ kqv,
                                                   unsigned short* __restrict__ vT) {
  int b = blockIdx.z;
  int t0 = blockIdx.x * 64;
  int c0 = blockIdx.y * 64;
  __shared__ unsigned short tile[64][68];
  int tid = threadIdx.x;
#pragma unroll
  for (int i = 0; i < 4; ++i) {
    int idx = i * 256 + tid;
    int r = idx >> 4;
    int c4 = (idx & 15) * 4;
    const unsigned short* src = kqv + ((size_t)(b * 2048 + t0 + r)) * 3072 + 2048 + c0 + c4;
    us4 v = *(const us4*)src;
    *(us4*)&tile[r][c4] = v;
  }
  __syncthreads();
#pragma unroll
  for (int i = 0; i < 4; ++i) {
    int idx = i * 256 + tid;
    int rc = idx >> 4;
    int t4 = (idx & 15) * 4;
    us4 v;
    v[0] = tile[t4 + 0][rc]; v[1] = tile[t4 + 1][rc];
    v[2] = tile[t4 + 2][rc]; v[3] = tile[t4 + 3][rc];
    unsigned short* dst = vT + ((size_t)(b * 1024 + c0 + rc)) * 2048 + t0 + t4;
    *(us4*)dst = v;
  }
}

// ---------------- g0: 256x192 BK=64 8-phase GEMM, 512 blocks = 2 rounds -------
// Staged/CU = 2 x (256+192)*1024*2B = 1.83MB (vs r13's 2.1MB at 128x384) at the
// measured ~14 B/cyc DMA rate. acc[8][3] = 96 f32 (same count as r13 -> no
// spill). LDS 112KB: 2 bufs x (A 32KB | B 24KB). 7 DMA ops/K-tile (A4+B3).
// Per-tile phases (reads in-phase before barrier; 12 MFMA each):
//  ph1 rd A(m0-3,kk0)+B(kk0), stg A(t+1)->other [2]
//  ph2 rd A(m0-3,kk1)+B(kk1), stg A(t+1)->other [2]
//  ph3 rd A(m4-7,kk0),        stg B(t+2)->own  [3]  (B fully read by ph2)
//  ph4 rd A(m4-7,kk1),        GATE vmcnt(3) [drain A(t+1), leave B(t+2)]
// XCD swizzle: bx = swz>>5 -> 2 B panels (768KB) resident per XCD L2.
__global__ __launch_bounds__(512, 2) void gemm_g0(
    const unsigned short* __restrict__ A, const unsigned short* __restrict__ B,
    unsigned short* __restrict__ C, const float* __restrict__ bias) {
  const int flat = blockIdx.x;
  const int swz = (flat & 7) * 64 + (flat >> 3);   // XCD-contiguous remap
  const int bx = swz >> 5;                          // 0..15
  const int by = swz & 31;                          // 0..31
  const int rowBase = by * 256, colBase = bx * 192;
  const int lda = 1024, ldc = 3072, nk = 16;

  __shared__ __align__(16) unsigned char lds[114688];  // 2 x (A 32K | B 24K)
  const int tid = threadIdx.x;
  const int lane = tid & 63, wid = tid >> 6;
  const int wr = wid >> 2, wc = wid & 3;
  const int l15 = lane & 15, l4 = lane >> 4, l7 = lane & 7;

  f32x4 acc[8][3] = {};
  bf16x8 a0[4], a1[4], a2[4], a3[4], bb0[3], bb1[3];

  const unsigned short* Ab = A + (size_t)rowBase * lda;
  const unsigned short* Bb = B + (size_t)colBase * lda;
  unsigned aoff[4], boff[3], aldso[4], bldso[3];
#pragma unroll
  for (int i = 0; i < 4; ++i) {
    int off = i * 8192 + tid * 16;
    int r = off >> 7;
    int sb = ((off >> 4) & 7) ^ (r & 7);
    aoff[i] = (unsigned)(r * lda + sb * 8);
    aldso[i] = (unsigned)off;
    if (i < 3) { boff[i] = aoff[i]; bldso[i] = (unsigned)off; }
  }

  auto STA = [&](int buf, int op, int koff) {
    async16(Ab + (size_t)(aoff[op] + (unsigned)koff), lds + buf * 57344 + aldso[op]);
  };
  auto STB = [&](int buf, int op, int koff) {
    async16(Bb + (size_t)(boff[op] + (unsigned)koff),
            lds + buf * 57344 + 32768 + bldso[op]);
  };
  auto RA = [&](int buf, int m, int kk) -> bf16x8 {
    int row = wr * 128 + m * 16 + l15;
    int blk = (kk * 4 + l4) ^ l7;
    return *(const bf16x8*)(lds + buf * 57344 + row * 128 + blk * 16);
  };
  auto RB = [&](int buf, int n, int kk) -> bf16x8 {
    int row = wc * 48 + n * 16 + l15;
    int blk = (kk * 4 + l4) ^ l7;
    return *(const bf16x8*)(lds + buf * 57344 + 32768 + row * 128 + blk * 16);
  };

#define RDA4(dst, BUF, MH, KK)                                                 \
  _Pragma("unroll") for (int mi = 0; mi < 4; ++mi) dst[mi] = RA((BUF), (MH) * 4 + mi, (KK))
#define RDB3(dst, BUF, KK)                                                     \
  _Pragma("unroll") for (int nj = 0; nj < 3; ++nj) dst[nj] = RB((BUF), nj, (KK))

#define MQ(MB, AF, BF)                                                         \
  _Pragma("unroll") for (int mi = 0; mi < 4; ++mi)                             \
  _Pragma("unroll") for (int nj = 0; nj < 3; ++nj)                             \
      acc[(MB) + mi][nj] = __builtin_amdgcn_mfma_f32_16x16x32_bf16(            \
          AF[mi], BF[nj], acc[(MB) + mi][nj], 0, 0, 0)

#define PHASE(RDS, STG, GATE, MB, AF, BF)                                      \
  do {                                                                         \
    RDS;                                                                       \
    STG;                                                                       \
    BARM();                                                                    \
    LGKM0();                                                                   \
    SCHEDB();                                                                  \
    __builtin_amdgcn_s_setprio(1);                                             \
    MQ(MB, AF, BF);                                                            \
    __builtin_amdgcn_s_setprio(0);                                             \
    GATE;                                                                      \
    BARM();                                                                    \
  } while (0)

  // prologue: A(0),B(0)->buf0 (7 ops), B(1)->buf1 (3 ops); gate leaves B(1)
#pragma unroll
  for (int i = 0; i < 4; ++i) STA(0, i, 0);
#pragma unroll
  for (int i = 0; i < 3; ++i) STB(0, i, 0);
#pragma unroll
  for (int i = 0; i < 3; ++i) STB(1, i, 64);
  VMCNT3();
  BARM();

  for (int it = 0; it < 8; ++it) {
    int t = it * 2;
    int kA1 = (t + 1) * 64;
    int k2 = (t + 2 < nk - 1 ? t + 2 : nk - 1) * 64;
    int k3 = (t + 3 < nk - 1 ? t + 3 : nk - 1) * 64;
    // tile t from buf0
    PHASE({ RDA4(a0, 0, 0, 0); RDB3(bb0, 0, 0); }, { STA(1, 0, kA1); STA(1, 1, kA1); },
          (void)0, 0, a0, bb0);
    PHASE({ RDA4(a1, 0, 0, 1); RDB3(bb1, 0, 1); }, { STA(1, 2, kA1); STA(1, 3, kA1); },
          (void)0, 0, a1, bb1);
    PHASE({ RDA4(a2, 0, 1, 0); }, { STB(0, 0, k2); STB(0, 1, k2); STB(0, 2, k2); },
          (void)0, 4, a2, bb0);
    PHASE({ RDA4(a3, 0, 1, 1); }, (void)0, VMCNT3(), 4, a3, bb1);
    // tile t+1 from buf1
    PHASE({ RDA4(a0, 1, 0, 0); RDB3(bb0, 1, 0); }, { STA(0, 0, k2); STA(0, 1, k2); },
          (void)0, 0, a0, bb0);
    PHASE({ RDA4(a1, 1, 0, 1); RDB3(bb1, 1, 1); }, { STA(0, 2, k2); STA(0, 3, k2); },
          (void)0, 0, a1, bb1);
    PHASE({ RDA4(a2, 1, 1, 0); }, { STB(1, 0, k3); STB(1, 1, k3); STB(1, 2, k3); },
          (void)0, 4, a2, bb0);
    PHASE({ RDA4(a3, 1, 1, 1); }, (void)0, VMCNT3(), 4, a3, bb1);
  }
#undef PHASE
#undef MQ
#undef RDA4
#undef RDB3

  const int cr = l4 * 4;
#pragma unroll
  for (int n = 0; n < 3; ++n) {
    int col = colBase + wc * 48 + n * 16 + l15;
    float bv = bias[col];
#pragma unroll
    for (int m = 0; m < 8; ++m) {
      int row = rowBase + wr * 128 + m * 16 + cr;
#pragma unroll
      for (int i = 0; i < 4; ++i)
        C[(size_t)(row + i) * ldc + col] = f2bf(acc[m][n][i] + bv);
    }
  }
}

// ---------------- g1: 256x256 8-phase GEMM, S = (k@q^T)*scale, causal skip ----
__global__ __launch_bounds__(512, 2) void gemm_s(
    const unsigned short* __restrict__ A, int lda, long long sA,
    const unsigned short* __restrict__ B, int ldb, long long sB,
    unsigned short* __restrict__ C, int ldc, long long sC,
    float scale, int K) {
  int bx = blockIdx.x, by = blockIdx.y;
  const int bz = blockIdx.z;
  if (bx > by) return;
  A += (size_t)bz * sA;
  B += (size_t)bz * sB;
  const int rowBase = by * 256;
  const int colBase = bx * 256;
  const int nk = K / 64;

  __shared__ __align__(16) unsigned char lds[131072];
  const int tid = threadIdx.x;
  const int lane = tid & 63;
  const int wid = tid >> 6;
  const int wr = wid >> 2;
  const int wc = wid & 3;
  const int l15 = lane & 15, l4 = lane >> 4, l7 = lane & 7;

  f32x4 acc[8][4] = {};
  bf16x8 af0[4][2], af1[4][2], bf0[2][2], bf1[2][2];

  const unsigned short* Ab = A + (size_t)rowBase * lda;
  const unsigned short* Bb = B + (size_t)colBase * ldb;
  unsigned loff[2][2];
  unsigned lldso[2];
#pragma unroll
  for (int i = 0; i < 2; ++i) {
    int off = (i * 512 + tid) * 16;
    int r = off >> 7;
    int sb = ((off >> 4) & 7) ^ (r & 7);
    lldso[i] = (unsigned)off;
#pragma unroll
    for (int hh = 0; hh < 2; ++hh)
      loff[hh][i] = (unsigned)((hh * 128 + r) * lda + sb * 8);
  }

  auto STAGE = [&](int bufc, int isB, int half, const unsigned short* Gb, int koff) {
#pragma unroll
    for (int i = 0; i < 2; ++i)
      async16(Gb + (size_t)(loff[half][i] + (unsigned)koff),
              lds + bufc * 65536 + isB * 32768 + half * 16384 + lldso[i]);
  };
  auto RDA = [&](int bufc, int m, int kk) -> bf16x8 {
    int row = m * 16 + l15;
    int blk = (kk * 4 + l4) ^ l7;
    return *(const bf16x8*)(lds + bufc * 65536 + wr * 16384 + row * 128 + blk * 16);
  };
  auto RDB = [&](int bufc, int n, int kk) -> bf16x8 {
    int row = (wc & 1) * 64 + n * 16 + l15;
    int blk = (kk * 4 + l4) ^ l7;
    return *(const bf16x8*)(lds + bufc * 65536 + 32768 + (wc >> 1) * 16384 +
                            row * 128 + blk * 16);
  };

#define RDA8(dst, BUF, Q)                                                      \
  _Pragma("unroll") for (int mi = 0; mi < 4; ++mi)                             \
  _Pragma("unroll") for (int kk = 0; kk < 2; ++kk)                             \
      dst[mi][kk] = RDA((BUF), (Q) * 4 + mi, kk)
#define RDB4(dst, BUF, NB)                                                     \
  _Pragma("unroll") for (int nj = 0; nj < 2; ++nj)                             \
  _Pragma("unroll") for (int kk = 0; kk < 2; ++kk)                             \
      dst[nj][kk] = RDB((BUF), (NB) + nj, kk)

#define MFMAQ(MB, NB, AF, BF)                                                  \
  _Pragma("unroll") for (int kk = 0; kk < 2; ++kk)                             \
  _Pragma("unroll") for (int mi = 0; mi < 4; ++mi)                             \
  _Pragma("unroll") for (int nj = 0; nj < 2; ++nj)                             \
      acc[(MB) + mi][(NB) + nj] = __builtin_amdgcn_mfma_f32_16x16x32_bf16(     \
          AF[mi][kk], BF[nj][kk], acc[(MB) + mi][(NB) + nj], 0, 0, 0)

#define PH(RDS, STG, HINT, GATE, MB, NB, AF, BF)                               \
  do {                                                                         \
    RDS;                                                                       \
    STG;                                                                       \
    HINT;                                                                      \
    BARM();                                                                    \
    LGKM0();                                                                   \
    SCHEDB();                                                                  \
    __builtin_amdgcn_s_setprio(1);                                             \
    MFMAQ(MB, NB, AF, BF);                                                     \
    __builtin_amdgcn_s_setprio(0);                                             \
    GATE;                                                                      \
    BARM();                                                                    \
  } while (0)

  STAGE(0, 0, 0, Ab, 0);
  STAGE(0, 0, 1, Ab, 0);
  STAGE(0, 1, 0, Bb, 0);
  STAGE(0, 1, 1, Bb, 0);
  STAGE(1, 1, 0, Bb, 64);
  STAGE(1, 1, 1, Bb, 64);
  VMCNT4();
  BARM();

  const int nt2 = nk >> 1;
  for (int it = 0; it < nt2; ++it) {
    int t = it * 2;
    int kA1 = (t + 1) * 64;
    int k2 = (t + 2 < nk - 1 ? t + 2 : nk - 1) * 64;
    int k3 = (t + 3 < nk - 1 ? t + 3 : nk - 1) * 64;
    PH({ RDA8(af0, 0, 0); RDB4(bf0, 0, 0); }, STAGE(1, 0, 0, Ab, kA1), LGKM8(),
       (void)0, 0, 0, af0, bf0);
    PH({ RDB4(bf1, 0, 2); }, STAGE(1, 0, 1, Ab, kA1), (void)0,
       (void)0, 0, 2, af0, bf1);
    PH({ RDA8(af1, 0, 1); }, STAGE(0, 1, 0, Bb, k2), (void)0,
       (void)0, 4, 2, af1, bf1);
    PH({}, STAGE(0, 1, 1, Bb, k2), (void)0,
       VMCNT4(), 4, 0, af1, bf0);
    PH({ RDA8(af0, 1, 0); RDB4(bf0, 1, 0); }, STAGE(0, 0, 0, Ab, k2), LGKM8(),
       (void)0, 0, 0, af0, bf0);
    PH({ RDB4(bf1, 1, 2); }, STAGE(0, 0, 1, Ab, k2), (void)0,
       (void)0, 0, 2, af0, bf1);
    PH({ RDA8(af1, 1, 1); }, STAGE(1, 1, 0, Bb, k3), (void)0,
       (void)0, 4, 2, af1, bf1);
    PH({}, STAGE(1, 1, 1, Bb, k3), (void)0,
       VMCNT4(), 4, 0, af1, bf0);
  }
#undef PH
#undef MFMAQ
#undef RDA8
#undef RDB4

  const int cr = l4 * 4;
  unsigned short* Cb = C + (size_t)bz * sC;
#pragma unroll
  for (int n = 0; n < 4; ++n) {
    int col = colBase + wc * 64 + n * 16 + l15;
#pragma unroll
    for (int m = 0; m < 8; ++m) {
      int row = rowBase + wr * 128 + m * 16 + cr;
#pragma unroll
      for (int i = 0; i < 4; ++i)
        Cb[(size_t)(row + i) * ldc + col] = f2bf(acc[m][n][i] * scale);
    }
  }
}

// ---------------- g2: two-chain pv (r13 4-wave proven version) ----------------
__global__ __launch_bounds__(256, 2) void gemm_pv2(
    const unsigned short* __restrict__ S, const unsigned short* __restrict__ V,
    float* __restrict__ O) {
  const int f = blockIdx.x;
  const int bx = f & 7;
  const int p = (f >> 3) & 7;
  const int bz = f >> 6;
  const int byH = 15 - p;
  const int nkL = 2 * (p + 1);
  const int nkH = 32 - 2 * p;
  const unsigned short* base = S + (size_t)bz * 2048 * 2048;
  const unsigned short* AH = base + (size_t)(byH * 128) * 2048;
  const unsigned short* AL = base + (size_t)(p * 128) * 2048;
  const unsigned short* Bb = V + (size_t)bz * 1024 * 2048 + (size_t)(bx * 128) * 2048;
  float* Ob = O + (size_t)bz * 2048 * 1024;

  __shared__ __align__(16) unsigned char lds[65536];
  const int tid = threadIdx.x;
  const int lane = tid & 63, wid = tid >> 6;
  const int wr = (wid >> 1) * 64, wc = (wid & 1) * 64;
  const int l15 = lane & 15, l4 = lane >> 4, l7 = lane & 7;

  f32x4 accH[4][4] = {}, accL[4][4] = {};

  unsigned goff[4], ldso[4];
#pragma unroll
  for (int ii = 0; ii < 4; ++ii) {
    int off = (ii * 256 + tid) * 16;
    int rr = off >> 7;
    int sb = ((off >> 4) & 7) ^ (rr & 7);
    goff[ii] = (unsigned)(rr * 2048 + sb * 8);
    ldso[ii] = (unsigned)off;
  }

  auto ST = [&](int buf, const unsigned short* Ap, unsigned kof) {
#pragma unroll
    for (int ii = 0; ii < 4; ++ii) {
      async16(Ap + (size_t)(goff[ii] + kof), lds + buf * 32768 + ldso[ii]);
      async16(Bb + (size_t)(goff[ii] + kof), lds + buf * 32768 + 16384 + ldso[ii]);
    }
  };
  auto ITEM = [&](int i, const unsigned short*& P, unsigned& kf) {
    if (i < 2 * nkL) {
      P = (i & 1) ? AL : AH;
      kf = (unsigned)((i >> 1) * 64);
    } else {
      P = AH;
      kf = (unsigned)((i - nkL) * 64);
    }
  };

#define PVSTEP(BUF, ACC, NITEM)                                                \
  do {                                                                         \
    const unsigned short* nP;                                                  \
    unsigned nK;                                                               \
    ITEM((NITEM) < 33 ? (NITEM) : 33, nP, nK);                                 \
    VMCNT8();                                                                  \
    BARM();                                                                    \
    bf16x8 af[4][2], bfr[4][2];                                                \
    _Pragma("unroll") for (int m = 0; m < 4; ++m) {                            \
      int row = wr + m * 16 + l15;                                             \
      _Pragma("unroll") for (int kk = 0; kk < 2; ++kk)                         \
        af[m][kk] = *(const bf16x8*)(lds + (BUF) * 32768 + row * 128 +         \
                                     (((kk * 4 + l4) ^ l7) * 16));             \
    }                                                                          \
    _Pragma("unroll") for (int n = 0; n < 4; ++n) {                            \
      int row = wc + n * 16 + l15;                                             \
      _Pragma("unroll") for (int kk = 0; kk < 2; ++kk)                         \
        bfr[n][kk] = *(const bf16x8*)(lds + (BUF) * 32768 + 16384 + row * 128 +\
                                      (((kk * 4 + l4) ^ l7) * 16));            \
    }                                                                          \
    LGKM0();                                                                   \
    BARM();                                                                    \
    ST((BUF), nP, nK);                                                         \
    SCHEDB();                                                                  \
    __builtin_amdgcn_s_setprio(1);                                             \
    _Pragma("unroll") for (int kk = 0; kk < 2; ++kk)                           \
    _Pragma("unroll") for (int m = 0; m < 4; ++m)                              \
    _Pragma("unroll") for (int n = 0; n < 4; ++n)                              \
      ACC[m][n] = __builtin_amdgcn_mfma_f32_16x16x32_bf16(af[m][kk], bfr[n][kk],\
                                                          ACC[m][n], 0, 0, 0); \
    __builtin_amdgcn_s_setprio(0);                                             \
  } while (0)

  ST(0, AH, 0);
  {
    const unsigned short* P; unsigned kf;
    ITEM(1, P, kf);
    ST(1, P, kf);
  }

  for (int t = 0; t < nkL; ++t) {
    PVSTEP(0, accH, 2 * t + 2);
    PVSTEP(1, accL, 2 * t + 3);
  }
  for (int u = nkL; u < nkH; u += 2) {
    PVSTEP(0, accH, u + nkL + 2);
    PVSTEP(1, accH, u + nkL + 3);
  }
#undef PVSTEP

  const int cr = l4 * 4;
#pragma unroll
  for (int n = 0; n < 4; ++n) {
    int col = bx * 128 + wc + n * 16 + l15;
#pragma unroll
    for (int m = 0; m < 4; ++m) {
      int rH = byH * 128 + wr + m * 16 + cr;
      int rL = p * 128 + wr + m * 16 + cr;
#pragma unroll
      for (int i = 0; i < 4; ++i) {
        Ob[(size_t)(rH + i) * 1024 + col] = accH[m][n][i];
        Ob[(size_t)(rL + i) * 1024 + col] = accL[m][n][i];
      }
    }
  }
}

// ---------------- causal softmax over S rows (in place, bf16) ----------------
__global__ __launch_bounds__(256) void softmax_causal(unsigned short* __restrict__ S) {
  const int T = 2048;
  int t = blockIdx.x, b = blockIdx.y;
  unsigned short* row = S + ((size_t)b * T + t) * T;
  const int nv = t + 1;
  const int bound = ((t >> 7) + 1) << 7;
  int tid = threadIdx.x;
  int lane = tid & 63, wid = tid >> 6;
  int s0 = tid * 8;
  us8 raw = {};
  if (s0 < nv) raw = *(const us8*)(row + s0);
  float v[8];
  float m = -3.0e38f;
#pragma unroll
  for (int j = 0; j < 8; ++j) {
    v[j] = bf2f(raw[j]);
    if (s0 + j < nv) m = fmaxf(m, v[j]);
  }
#pragma unroll
  for (int o = 32; o > 0; o >>= 1) m = fmaxf(m, __shfl_xor(m, o, 64));
  __shared__ float red[4];
  if (lane == 0) red[wid] = m;
  __syncthreads();
  m = fmaxf(fmaxf(red[0], red[1]), fmaxf(red[2], red[3]));
  __syncthreads();
  float sum = 0.f;
#pragma unroll
  for (int j = 0; j < 8; ++j) {
    float e = (s0 + j < nv) ? exp2f(v[j] - m) : 0.f;
    v[j] = e;
    sum += e;
  }
#pragma unroll
  for (int o = 32; o > 0; o >>= 1) sum += __shfl_xor(sum, o, 64);
  if (lane == 0) red[wid] = sum;
  __syncthreads();
  sum = red[0] + red[1] + red[2] + red[3];
  float inv = 1.0f / sum;
  if (s0 < bound) {
    us8 outv;
#pragma unroll
    for (int j = 0; j < 8; ++j) outv[j] = f2bf(v[j] * inv);
    *(us8*)(row + s0) = outv;
  }
}

extern "C" void kernel_launch(void* const* d_in, const int* in_sizes, int n_in,
                              void* d_out, int out_size, void* d_ws, size_t ws_size,
                              hipStream_t stream) {
  const float* x = (const float*)d_in[0];      // [4,2048,1024]
  const float* W = (const float*)d_in[1];      // [3072,1024]
  const float* bias = (const float*)d_in[2];   // [3072]
  float* out = (float*)d_out;                  // [4,2048,1024]

  char* ws = (char*)d_ws;
  if (ws_size < 106954752u) return;
  unsigned short* xbf = (unsigned short*)(ws);
  unsigned short* vT = xbf;  // alias: xbf dead after gemm_g0
  unsigned short* wbf = (unsigned short*)(ws + 16777216);
  unsigned short* kqv = (unsigned short*)(ws + 23068672);
  unsigned short* S = (unsigned short*)(ws + 73400320);

  const float kSoftmaxScale = 1.4426950408889634f / 32.0f;  // log2(e)/sqrt(1024)

  cvt_bf16_2<<<11264, 256, 0, stream>>>(x, xbf, 2097152, W, wbf, 786432);

  // kqv = x @ W^T + b : 256x192 tiles, 32x16 = 512 blocks = 2 exact rounds
  gemm_g0<<<dim3(512, 1, 1), 512, 0, stream>>>(xbf, wbf, kqv, bias);

  transpose_v<<<dim3(32, 16, 4), 256, 0, stream>>>(kqv, vT);

  // S = (k @ q^T) * log2e/32 (bf16), causal blocks skipped
  gemm_s<<<dim3(8, 8, 4), 512, 0, stream>>>(
      kqv, 3072, 2048LL * 3072, kqv + 1024, 3072, 2048LL * 3072,
      S, 2048, 2048LL * 2048, kSoftmaxScale, 1024);

  softmax_causal<<<dim3(2048, 4), 256, 0, stream>>>(S);

  // out = P @ vT^T (fp32): two-chain blocks, uniform 34 K-tiles, 256 = 1/CU
  gemm_pv2<<<dim3(256, 1, 1), 256, 0, stream>>>(S, vT, out);
}

// Round 17
// 169.078 us; speedup vs baseline: 1.0505x; 1.0013x over previous
//
#include <hip/hip_runtime.h>

typedef __bf16 bf16x8 __attribute__((ext_vector_type(8)));
typedef float f32x4 __attribute__((ext_vector_type(4)));
typedef float fl4 __attribute__((ext_vector_type(4)));
typedef unsigned short us4 __attribute__((ext_vector_type(4)));
typedef unsigned short us8 __attribute__((ext_vector_type(8)));

__device__ __forceinline__ unsigned short f2bf(float f) {
  unsigned u = __builtin_bit_cast(unsigned, f);
  u += 0x7fffu + ((u >> 16) & 1u);
  return (unsigned short)(u >> 16);
}
__device__ __forceinline__ float bf2f(unsigned short h) {
  unsigned u = ((unsigned)h) << 16;
  return __builtin_bit_cast(float, u);
}

__device__ __forceinline__ void async16(const void* g, void* l) {
  __builtin_amdgcn_global_load_lds(
      (const __attribute__((address_space(1))) unsigned int*)g,
      (__attribute__((address_space(3))) unsigned int*)l, 16, 0, 0);
}

#define BARM() asm volatile("s_barrier" ::: "memory")
#define VMCNT4() asm volatile("s_waitcnt vmcnt(4)" ::: "memory")
#define VMCNT6() asm volatile("s_waitcnt vmcnt(6)" ::: "memory")
#define VMCNT8() asm volatile("s_waitcnt vmcnt(8)" ::: "memory")
#define LGKM0() asm volatile("s_waitcnt lgkmcnt(0)" ::: "memory")
#define LGKM8() asm volatile("s_waitcnt lgkmcnt(8)" ::: "memory")
#define SCHEDB() __builtin_amdgcn_sched_barrier(0)

// ---------------- fp32 -> bf16 convert (x and W merged) ----------------
__global__ __launch_bounds__(256) void cvt_bf16_2(const float* __restrict__ sA,
                                                  unsigned short* __restrict__ dA, int nA,
                                                  const float* __restrict__ sB,
                                                  unsigned short* __restrict__ dB, int nB) {
  int i = blockIdx.x * 256 + threadIdx.x;
  const float* s;
  unsigned short* d;
  if (i < nA) {
    s = sA; d = dA;
  } else {
    i -= nA;
    if (i >= nB) return;
    s = sB; d = dB;
  }
  fl4 f = ((const fl4*)s)[i];
  us4 o;
  o[0] = f2bf(f[0]); o[1] = f2bf(f[1]); o[2] = f2bf(f[2]); o[3] = f2bf(f[3]);
  ((us4*)d)[i] = o;
}

// ---------------- transpose v: vT[b][c][t] = kqv[b*2048+t][2048+c] ----------------
__global__ __launch_bounds__(256) void transpose_v(const unsigned short* __restrict__ kqv,
                                                   unsigned short* __restrict__ vT) {
  int b = blockIdx.z;
  int t0 = blockIdx.x * 64;
  int c0 = blockIdx.y * 64;
  __shared__ unsigned short tile[64][68];
  int tid = threadIdx.x;
#pragma unroll
  for (int i = 0; i < 4; ++i) {
    int idx = i * 256 + tid;
    int r = idx >> 4;
    int c4 = (idx & 15) * 4;
    const unsigned short* src = kqv + ((size_t)(b * 2048 + t0 + r)) * 3072 + 2048 + c0 + c4;
    us4 v = *(const us4*)src;
    *(us4*)&tile[r][c4] = v;
  }
  __syncthreads();
#pragma unroll
  for (int i = 0; i < 4; ++i) {
    int idx = i * 256 + tid;
    int rc = idx >> 4;
    int t4 = (idx & 15) * 4;
    us4 v;
    v[0] = tile[t4 + 0][rc]; v[1] = tile[t4 + 1][rc];
    v[2] = tile[t4 + 2][rc]; v[3] = tile[t4 + 3][rc];
    unsigned short* dst = vT + ((size_t)(b * 1024 + c0 + rc)) * 2048 + t0 + t4;
    *(us4*)dst = v;
  }
}

// ---------------- g0: 128x384 8-phase GEMM, 512 blocks = 2 exact rounds -------
// (r13 proven: 62.6us; DMA-staging-rate-limited ~14 B/cyc/CU; geometry optimum)
__global__ __launch_bounds__(512, 2) void gemm_g0(
    const unsigned short* __restrict__ A, const unsigned short* __restrict__ B,
    unsigned short* __restrict__ C, const float* __restrict__ bias) {
  const int flat = blockIdx.x;
  const int swz = (flat & 7) * 64 + (flat >> 3);   // XCD-contiguous remap
  const int bx = swz & 7;
  const int by = swz >> 3;
  const int rowBase = by * 128, colBase = bx * 384;
  const int lda = 1024, ldc = 3072, nk = 16;

  __shared__ __align__(16) unsigned char lds[131072];
  const int tid = threadIdx.x;
  const int lane = tid & 63, wid = tid >> 6;
  const int wr = wid >> 2, wc = wid & 3;
  const int l15 = lane & 15, l4 = lane >> 4, l7 = lane & 7;

  f32x4 acc[4][6] = {};
  bf16x8 af01[2][2], af23[2][2], bf[6][2];

  const unsigned short* Ab = A + (size_t)rowBase * lda;
  const unsigned short* Bb = B + (size_t)colBase * lda;
  unsigned aoff[2], boff[6], aldso[2], bldso[6];
#pragma unroll
  for (int i = 0; i < 6; ++i) {
    int off = i * 8192 + tid * 16;
    int r = off >> 7;
    int sb = ((off >> 4) & 7) ^ (r & 7);
    if (i < 2) { aoff[i] = (unsigned)(r * lda + sb * 8); aldso[i] = (unsigned)off; }
    boff[i] = (unsigned)(r * lda + sb * 8);
    bldso[i] = (unsigned)off;
  }

  auto STA = [&](int bufc, int op, int koff) {
    async16(Ab + (size_t)(aoff[op] + (unsigned)koff), lds + bufc * 65536 + aldso[op]);
  };
  auto STB = [&](int bufc, int op, int koff) {
    async16(Bb + (size_t)(boff[op] + (unsigned)koff),
            lds + bufc * 65536 + 16384 + bldso[op]);
  };
  auto RA = [&](int bufc, int m, int kk) -> bf16x8 {
    int row = wr * 64 + m * 16 + l15;
    int blk = (kk * 4 + l4) ^ l7;
    return *(const bf16x8*)(lds + bufc * 65536 + row * 128 + blk * 16);
  };
  auto RB = [&](int bufc, int n, int kk) -> bf16x8 {
    int row = wc * 96 + n * 16 + l15;
    int blk = (kk * 4 + l4) ^ l7;
    return *(const bf16x8*)(lds + bufc * 65536 + 16384 + row * 128 + blk * 16);
  };

#define RD_A01(BUF)                                                            \
  _Pragma("unroll") for (int mi = 0; mi < 2; ++mi)                             \
  _Pragma("unroll") for (int kk = 0; kk < 2; ++kk) af01[mi][kk] = RA((BUF), mi, kk)
#define RD_A23(BUF)                                                            \
  _Pragma("unroll") for (int mi = 0; mi < 2; ++mi)                             \
  _Pragma("unroll") for (int kk = 0; kk < 2; ++kk) af23[mi][kk] = RA((BUF), 2 + mi, kk)
#define RD_B(BUF, N0)                                                          \
  _Pragma("unroll") for (int nj = 0; nj < 3; ++nj)                             \
  _Pragma("unroll") for (int kk = 0; kk < 2; ++kk) bf[(N0) + nj][kk] = RB((BUF), (N0) + nj, kk)

#define MQ(MB, NB, AF)                                                         \
  _Pragma("unroll") for (int kk = 0; kk < 2; ++kk)                             \
  _Pragma("unroll") for (int mi = 0; mi < 2; ++mi)                             \
  _Pragma("unroll") for (int nj = 0; nj < 3; ++nj)                             \
      acc[(MB) + mi][(NB) + nj] = __builtin_amdgcn_mfma_f32_16x16x32_bf16(     \
          AF[mi][kk], bf[(NB) + nj][kk], acc[(MB) + mi][(NB) + nj], 0, 0, 0)

#define PHASE(RDS, STG, GATE, MB, NB, AF)                                      \
  do {                                                                         \
    RDS;                                                                       \
    STG;                                                                       \
    BARM();                                                                    \
    LGKM0();                                                                   \
    SCHEDB();                                                                  \
    __builtin_amdgcn_s_setprio(1);                                             \
    MQ(MB, NB, AF);                                                            \
    __builtin_amdgcn_s_setprio(0);                                             \
    GATE;                                                                      \
    BARM();                                                                    \
  } while (0)

  STA(0, 0, 0); STA(0, 1, 0);
#pragma unroll
  for (int i = 0; i < 6; ++i) STB(0, i, 0);
#pragma unroll
  for (int i = 0; i < 6; ++i) STB(1, i, 64);
  VMCNT6();
  BARM();

  for (int it = 0; it < 8; ++it) {
    int t = it * 2;
    int kA1 = (t + 1) * 64;
    int k2 = (t + 2 < nk - 1 ? t + 2 : nk - 1) * 64;
    int k3 = (t + 3 < nk - 1 ? t + 3 : nk - 1) * 64;
    PHASE({ RD_A01(0); RD_B(0, 0); }, { STA(1, 0, kA1); STA(1, 1, kA1); },
          (void)0, 0, 0, af01);
    PHASE({ RD_A23(0); RD_B(0, 3); }, (void)0, (void)0, 0, 3, af01);
    PHASE({}, { STB(0, 0, k2); STB(0, 1, k2); STB(0, 2, k2); },
          (void)0, 2, 3, af23);
    PHASE({}, { STB(0, 3, k2); STB(0, 4, k2); STB(0, 5, k2); },
          VMCNT6(), 2, 0, af23);
    PHASE({ RD_A01(1); RD_B(1, 0); }, { STA(0, 0, k2); STA(0, 1, k2); },
          (void)0, 0, 0, af01);
    PHASE({ RD_A23(1); RD_B(1, 3); }, (void)0, (void)0, 0, 3, af01);
    PHASE({}, { STB(1, 0, k3); STB(1, 1, k3); STB(1, 2, k3); },
          (void)0, 2, 3, af23);
    PHASE({}, { STB(1, 3, k3); STB(1, 4, k3); STB(1, 5, k3); },
          VMCNT6(), 2, 0, af23);
  }
#undef PHASE
#undef MQ
#undef RD_A01
#undef RD_A23
#undef RD_B

  const int cr = l4 * 4;
#pragma unroll
  for (int n = 0; n < 6; ++n) {
    int col = colBase + wc * 96 + n * 16 + l15;
    float bv = bias[col];
#pragma unroll
    for (int m = 0; m < 4; ++m) {
      int row = rowBase + wr * 64 + m * 16 + cr;
#pragma unroll
      for (int i = 0; i < 4; ++i)
        C[(size_t)(row + i) * ldc + col] = f2bf(acc[m][n][i] + bv);
    }
  }
}

// ---------------- g1: 256x256 8-phase GEMM, S = (k@q^T)*scale, causal skip ----
__global__ __launch_bounds__(512, 2) void gemm_s(
    const unsigned short* __restrict__ A, int lda, long long sA,
    const unsigned short* __restrict__ B, int ldb, long long sB,
    unsigned short* __restrict__ C, int ldc, long long sC,
    float scale, int K) {
  int bx = blockIdx.x, by = blockIdx.y;
  const int bz = blockIdx.z;
  if (bx > by) return;
  A += (size_t)bz * sA;
  B += (size_t)bz * sB;
  const int rowBase = by * 256;
  const int colBase = bx * 256;
  const int nk = K / 64;

  __shared__ __align__(16) unsigned char lds[131072];
  const int tid = threadIdx.x;
  const int lane = tid & 63;
  const int wid = tid >> 6;
  const int wr = wid >> 2;
  const int wc = wid & 3;
  const int l15 = lane & 15, l4 = lane >> 4, l7 = lane & 7;

  f32x4 acc[8][4] = {};
  bf16x8 af0[4][2], af1[4][2], bf0[2][2], bf1[2][2];

  const unsigned short* Ab = A + (size_t)rowBase * lda;
  const unsigned short* Bb = B + (size_t)colBase * ldb;
  unsigned loff[2][2];
  unsigned lldso[2];
#pragma unroll
  for (int i = 0; i < 2; ++i) {
    int off = (i * 512 + tid) * 16;
    int r = off >> 7;
    int sb = ((off >> 4) & 7) ^ (r & 7);
    lldso[i] = (unsigned)off;
#pragma unroll
    for (int hh = 0; hh < 2; ++hh)
      loff[hh][i] = (unsigned)((hh * 128 + r) * lda + sb * 8);
  }

  auto STAGE = [&](int bufc, int isB, int half, const unsigned short* Gb, int koff) {
#pragma unroll
    for (int i = 0; i < 2; ++i)
      async16(Gb + (size_t)(loff[half][i] + (unsigned)koff),
              lds + bufc * 65536 + isB * 32768 + half * 16384 + lldso[i]);
  };
  auto RDA = [&](int bufc, int m, int kk) -> bf16x8 {
    int row = m * 16 + l15;
    int blk = (kk * 4 + l4) ^ l7;
    return *(const bf16x8*)(lds + bufc * 65536 + wr * 16384 + row * 128 + blk * 16);
  };
  auto RDB = [&](int bufc, int n, int kk) -> bf16x8 {
    int row = (wc & 1) * 64 + n * 16 + l15;
    int blk = (kk * 4 + l4) ^ l7;
    return *(const bf16x8*)(lds + bufc * 65536 + 32768 + (wc >> 1) * 16384 +
                            row * 128 + blk * 16);
  };

#define RDA8(dst, BUF, Q)                                                      \
  _Pragma("unroll") for (int mi = 0; mi < 4; ++mi)                             \
  _Pragma("unroll") for (int kk = 0; kk < 2; ++kk)                             \
      dst[mi][kk] = RDA((BUF), (Q) * 4 + mi, kk)
#define RDB4(dst, BUF, NB)                                                     \
  _Pragma("unroll") for (int nj = 0; nj < 2; ++nj)                             \
  _Pragma("unroll") for (int kk = 0; kk < 2; ++kk)                             \
      dst[nj][kk] = RDB((BUF), (NB) + nj, kk)

#define MFMAQ(MB, NB, AF, BF)                                                  \
  _Pragma("unroll") for (int kk = 0; kk < 2; ++kk)                             \
  _Pragma("unroll") for (int mi = 0; mi < 4; ++mi)                             \
  _Pragma("unroll") for (int nj = 0; nj < 2; ++nj)                             \
      acc[(MB) + mi][(NB) + nj] = __builtin_amdgcn_mfma_f32_16x16x32_bf16(     \
          AF[mi][kk], BF[nj][kk], acc[(MB) + mi][(NB) + nj], 0, 0, 0)

#define PH(RDS, STG, HINT, GATE, MB, NB, AF, BF)                               \
  do {                                                                         \
    RDS;                                                                       \
    STG;                                                                       \
    HINT;                                                                      \
    BARM();                                                                    \
    LGKM0();                                                                   \
    SCHEDB();                                                                  \
    __builtin_amdgcn_s_setprio(1);                                             \
    MFMAQ(MB, NB, AF, BF);                                                     \
    __builtin_amdgcn_s_setprio(0);                                             \
    GATE;                                                                      \
    BARM();                                                                    \
  } while (0)

  STAGE(0, 0, 0, Ab, 0);
  STAGE(0, 0, 1, Ab, 0);
  STAGE(0, 1, 0, Bb, 0);
  STAGE(0, 1, 1, Bb, 0);
  STAGE(1, 1, 0, Bb, 64);
  STAGE(1, 1, 1, Bb, 64);
  VMCNT4();
  BARM();

  const int nt2 = nk >> 1;
  for (int it = 0; it < nt2; ++it) {
    int t = it * 2;
    int kA1 = (t + 1) * 64;
    int k2 = (t + 2 < nk - 1 ? t + 2 : nk - 1) * 64;
    int k3 = (t + 3 < nk - 1 ? t + 3 : nk - 1) * 64;
    PH({ RDA8(af0, 0, 0); RDB4(bf0, 0, 0); }, STAGE(1, 0, 0, Ab, kA1), LGKM8(),
       (void)0, 0, 0, af0, bf0);
    PH({ RDB4(bf1, 0, 2); }, STAGE(1, 0, 1, Ab, kA1), (void)0,
       (void)0, 0, 2, af0, bf1);
    PH({ RDA8(af1, 0, 1); }, STAGE(0, 1, 0, Bb, k2), (void)0,
       (void)0, 4, 2, af1, bf1);
    PH({}, STAGE(0, 1, 1, Bb, k2), (void)0,
       VMCNT4(), 4, 0, af1, bf0);
    PH({ RDA8(af0, 1, 0); RDB4(bf0, 1, 0); }, STAGE(0, 0, 0, Ab, k2), LGKM8(),
       (void)0, 0, 0, af0, bf0);
    PH({ RDB4(bf1, 1, 2); }, STAGE(0, 0, 1, Ab, k2), (void)0,
       (void)0, 0, 2, af0, bf1);
    PH({ RDA8(af1, 1, 1); }, STAGE(1, 1, 0, Bb, k3), (void)0,
       (void)0, 4, 2, af1, bf1);
    PH({}, STAGE(1, 1, 1, Bb, k3), (void)0,
       VMCNT4(), 4, 0, af1, bf0);
  }
#undef PH
#undef MFMAQ
#undef RDA8
#undef RDB4

  const int cr = l4 * 4;
  unsigned short* Cb = C + (size_t)bz * sC;
#pragma unroll
  for (int n = 0; n < 4; ++n) {
    int col = colBase + wc * 64 + n * 16 + l15;
#pragma unroll
    for (int m = 0; m < 8; ++m) {
      int row = rowBase + wr * 128 + m * 16 + cr;
#pragma unroll
      for (int i = 0; i < 4; ++i)
        Cb[(size_t)(row + i) * ldc + col] = f2bf(acc[m][n][i] * scale);
    }
  }
}

// ---------------- g2: two-chain pv, 3-buffer single-barrier pipeline ----------
// 256 blocks = 1/CU; block owns chains by=15-p (32-2p tiles) + by=p (2p+2) =
// uniform 34 items. 3 bufs x 32KB: step s reads buf s%3, stages item s+2 into
// buf (s+2)%3 whose last readers (step s-1) are drained by the step-s barrier
// (each wave's MFMAs consumed its reads before reaching the barrier). One
// barrier per step; DMA issue overlaps reads+MFMA. Gate vmcnt(8): in-flight
// at step s start = [s:8, s+1:8] -> drain item s. Tail clamps to item 33.
__global__ __launch_bounds__(256, 1) void gemm_pv3(
    const unsigned short* __restrict__ S, const unsigned short* __restrict__ V,
    float* __restrict__ O) {
  const int f = blockIdx.x;
  const int bx = f & 7;
  const int p = (f >> 3) & 7;
  const int bz = f >> 6;
  const int byH = 15 - p;
  const int nkL = 2 * (p + 1);
  const int nkH = 32 - 2 * p;           // nkL + nkH = 34
  const unsigned short* base = S + (size_t)bz * 2048 * 2048;
  const unsigned short* AH = base + (size_t)(byH * 128) * 2048;
  const unsigned short* AL = base + (size_t)(p * 128) * 2048;
  const unsigned short* Bb = V + (size_t)bz * 1024 * 2048 + (size_t)(bx * 128) * 2048;
  float* Ob = O + (size_t)bz * 2048 * 1024;

  __shared__ __align__(16) unsigned char lds[98304];  // 3 bufs x (A16K | B16K)
  const int tid = threadIdx.x;
  const int lane = tid & 63, wid = tid >> 6;
  const int wr = (wid >> 1) * 64, wc = (wid & 1) * 64;
  const int l15 = lane & 15, l4 = lane >> 4, l7 = lane & 7;

  f32x4 accH[4][4] = {}, accL[4][4] = {};

  unsigned goff[4], ldso[4];
#pragma unroll
  for (int ii = 0; ii < 4; ++ii) {
    int off = (ii * 256 + tid) * 16;
    int rr = off >> 7;
    int sb = ((off >> 4) & 7) ^ (rr & 7);
    goff[ii] = (unsigned)(rr * 2048 + sb * 8);
    ldso[ii] = (unsigned)off;
  }

  auto ST = [&](int buf, const unsigned short* Ap, unsigned kof) {
#pragma unroll
    for (int ii = 0; ii < 4; ++ii) {
      async16(Ap + (size_t)(goff[ii] + kof), lds + buf * 32768 + ldso[ii]);
      async16(Bb + (size_t)(goff[ii] + kof), lds + buf * 32768 + 16384 + ldso[ii]);
    }
  };
  // item i (0..33): interleave region alternates H,L; then solo H.
  auto ITEM = [&](int i, const unsigned short*& P, unsigned& kf) {
    if (i < 2 * nkL) {
      P = (i & 1) ? AL : AH;
      kf = (unsigned)((i >> 1) * 64);
    } else {
      P = AH;
      kf = (unsigned)((i - nkL) * 64);
    }
  };

// step s: gate item s -> barrier -> issue item s+2 -> read buf s%3 -> 32 MFMA
#define PVSTEP(BUF, ACC, NITEM)                                                \
  do {                                                                         \
    const unsigned short* nP;                                                  \
    unsigned nK;                                                               \
    ITEM((NITEM) < 33 ? (NITEM) : 33, nP, nK);                                 \
    VMCNT8();                                                                  \
    BARM();                                                                    \
    ST(((NITEM) % 3), nP, nK);                                                 \
    bf16x8 af[4][2], bfr[4][2];                                                \
    _Pragma("unroll") for (int m = 0; m < 4; ++m) {                            \
      int row = wr + m * 16 + l15;                                             \
      _Pragma("unroll") for (int kk = 0; kk < 2; ++kk)                         \
        af[m][kk] = *(const bf16x8*)(lds + (BUF) * 32768 + row * 128 +         \
                                     (((kk * 4 + l4) ^ l7) * 16));             \
    }                                                                          \
    _Pragma("unroll") for (int n = 0; n < 4; ++n) {                            \
      int row = wc + n * 16 + l15;                                             \
      _Pragma("unroll") for (int kk = 0; kk < 2; ++kk)                         \
        bfr[n][kk] = *(const bf16x8*)(lds + (BUF) * 32768 + 16384 + row * 128 +\
                                      (((kk * 4 + l4) ^ l7) * 16));            \
    }                                                                          \
    __builtin_amdgcn_s_setprio(1);                                             \
    _Pragma("unroll") for (int kk = 0; kk < 2; ++kk)                           \
    _Pragma("unroll") for (int m = 0; m < 4; ++m)                              \
    _Pragma("unroll") for (int n = 0; n < 4; ++n)                              \
      ACC[m][n] = __builtin_amdgcn_mfma_f32_16x16x32_bf16(af[m][kk], bfr[n][kk],\
                                                          ACC[m][n], 0, 0, 0); \
    __builtin_amdgcn_s_setprio(0);                                             \
  } while (0)

  // prologue: items 0 -> buf0, 1 -> buf1
  ST(0, AH, 0);
  {
    const unsigned short* P; unsigned kf;
    ITEM(1, P, kf);
    ST(1, P, kf);
  }

  // steps: even = H (interleave) / solo-H; odd = L (interleave) / solo-H.
  // buffer for step s = s % 3; next item staged = s + 2.
  {
    int s = 0;
    for (; s < 2 * nkL; s += 2) {
      switch (s % 3) {                 // compile-time-ish small switch
        case 0: PVSTEP(0, accH, s + 2); PVSTEP(1, accL, s + 3); break;
        case 1: PVSTEP(1, accH, s + 2); PVSTEP(2, accL, s + 3); break;
        default: PVSTEP(2, accH, s + 2); PVSTEP(0, accL, s + 3); break;
      }
    }
    for (; s < 34; s += 2) {
      switch (s % 3) {
        case 0: PVSTEP(0, accH, s + 2); PVSTEP(1, accH, s + 3); break;
        case 1: PVSTEP(1, accH, s + 2); PVSTEP(2, accH, s + 3); break;
        default: PVSTEP(2, accH, s + 2); PVSTEP(0, accH, s + 3); break;
      }
    }
  }
#undef PVSTEP

  const int cr = l4 * 4;
#pragma unroll
  for (int n = 0; n < 4; ++n) {
    int col = bx * 128 + wc + n * 16 + l15;
#pragma unroll
    for (int m = 0; m < 4; ++m) {
      int rH = byH * 128 + wr + m * 16 + cr;
      int rL = p * 128 + wr + m * 16 + cr;
#pragma unroll
      for (int i = 0; i < 4; ++i) {
        Ob[(size_t)(rH + i) * 1024 + col] = accH[m][n][i];
        Ob[(size_t)(rL + i) * 1024 + col] = accL[m][n][i];
      }
    }
  }
}

// ---------------- causal softmax over S rows (in place, bf16) ----------------
__global__ __launch_bounds__(256) void softmax_causal(unsigned short* __restrict__ S) {
  const int T = 2048;
  int t = blockIdx.x, b = blockIdx.y;
  unsigned short* row = S + ((size_t)b * T + t) * T;
  const int nv = t + 1;
  const int bound = ((t >> 7) + 1) << 7;
  int tid = threadIdx.x;
  int lane = tid & 63, wid = tid >> 6;
  int s0 = tid * 8;
  us8 raw = {};
  if (s0 < nv) raw = *(const us8*)(row + s0);
  float v[8];
  float m = -3.0e38f;
#pragma unroll
  for (int j = 0; j < 8; ++j) {
    v[j] = bf2f(raw[j]);
    if (s0 + j < nv) m = fmaxf(m, v[j]);
  }
#pragma unroll
  for (int o = 32; o > 0; o >>= 1) m = fmaxf(m, __shfl_xor(m, o, 64));
  __shared__ float red[4];
  if (lane == 0) red[wid] = m;
  __syncthreads();
  m = fmaxf(fmaxf(red[0], red[1]), fmaxf(red[2], red[3]));
  __syncthreads();
  float sum = 0.f;
#pragma unroll
  for (int j = 0; j < 8; ++j) {
    float e = (s0 + j < nv) ? exp2f(v[j] - m) : 0.f;
    v[j] = e;
    sum += e;
  }
#pragma unroll
  for (int o = 32; o > 0; o >>= 1) sum += __shfl_xor(sum, o, 64);
  if (lane == 0) red[wid] = sum;
  __syncthreads();
  sum = red[0] + red[1] + red[2] + red[3];
  float inv = 1.0f / sum;
  if (s0 < bound) {
    us8 outv;
#pragma unroll
    for (int j = 0; j < 8; ++j) outv[j] = f2bf(v[j] * inv);
    *(us8*)(row + s0) = outv;
  }
}

extern "C" void kernel_launch(void* const* d_in, const int* in_sizes, int n_in,
                              void* d_out, int out_size, void* d_ws, size_t ws_size,
                              hipStream_t stream) {
  const float* x = (const float*)d_in[0];      // [4,2048,1024]
  const float* W = (const float*)d_in[1];      // [3072,1024]
  const float* bias = (const float*)d_in[2];   // [3072]
  float* out = (float*)d_out;                  // [4,2048,1024]

  char* ws = (char*)d_ws;
  if (ws_size < 106954752u) return;
  unsigned short* xbf = (unsigned short*)(ws);
  unsigned short* vT = xbf;  // alias: xbf dead after gemm_g0
  unsigned short* wbf = (unsigned short*)(ws + 16777216);
  unsigned short* kqv = (unsigned short*)(ws + 23068672);
  unsigned short* S = (unsigned short*)(ws + 73400320);

  const float kSoftmaxScale = 1.4426950408889634f / 32.0f;  // log2(e)/sqrt(1024)

  cvt_bf16_2<<<11264, 256, 0, stream>>>(x, xbf, 2097152, W, wbf, 786432);

  // kqv = x @ W^T + b : 128x384 tiles, 8x64 = 512 blocks = 2 exact rounds
  gemm_g0<<<dim3(512, 1, 1), 512, 0, stream>>>(xbf, wbf, kqv, bias);

  transpose_v<<<dim3(32, 16, 4), 256, 0, stream>>>(kqv, vT);

  // S = (k @ q^T) * log2e/32 (bf16), causal blocks skipped
  gemm_s<<<dim3(8, 8, 4), 512, 0, stream>>>(
      kqv, 3072, 2048LL * 3072, kqv + 1024, 3072, 2048LL * 3072,
      S, 2048, 2048LL * 2048, kSoftmaxScale, 1024);

  softmax_causal<<<dim3(2048, 4), 256, 0, stream>>>(S);

  // out = P @ vT^T (fp32): two-chain blocks, 3-buffer single-barrier pipeline
  gemm_pv3<<<dim3(256, 1, 1), 256, 0, stream>>>(S, vT, out);
}

// Round 18
// 167.139 us; speedup vs baseline: 1.0627x; 1.0116x over previous
//
#include <hip/hip_runtime.h>

typedef __bf16 bf16x8 __attribute__((ext_vector_type(8)));
typedef float f32x4 __attribute__((ext_vector_type(4)));
typedef float fl4 __attribute__((ext_vector_type(4)));
typedef unsigned short us4 __attribute__((ext_vector_type(4)));
typedef unsigned short us8 __attribute__((ext_vector_type(8)));

__device__ __forceinline__ unsigned short f2bf(float f) {
  unsigned u = __builtin_bit_cast(unsigned, f);
  u += 0x7fffu + ((u >> 16) & 1u);
  return (unsigned short)(u >> 16);
}
__device__ __forceinline__ float bf2f(unsigned short h) {
  unsigned u = ((unsigned)h) << 16;
  return __builtin_bit_cast(float, u);
}

__device__ __forceinline__ void async16(const void* g, void* l) {
  __builtin_amdgcn_global_load_lds(
      (const __attribute__((address_space(1))) unsigned int*)g,
      (__attribute__((address_space(3))) unsigned int*)l, 16, 0, 0);
}

#define BARM() asm volatile("s_barrier" ::: "memory")
#define VMCNT4() asm volatile("s_waitcnt vmcnt(4)" ::: "memory")
#define VMCNT6() asm volatile("s_waitcnt vmcnt(6)" ::: "memory")
#define VMCNT8() asm volatile("s_waitcnt vmcnt(8)" ::: "memory")
#define LGKM0() asm volatile("s_waitcnt lgkmcnt(0)" ::: "memory")
#define LGKM8() asm volatile("s_waitcnt lgkmcnt(8)" ::: "memory")
#define SCHEDB() __builtin_amdgcn_sched_barrier(0)

// ---------------- fp32 -> bf16 convert (x and W merged) ----------------
__global__ __launch_bounds__(256) void cvt_bf16_2(const float* __restrict__ sA,
                                                  unsigned short* __restrict__ dA, int nA,
                                                  const float* __restrict__ sB,
                                                  unsigned short* __restrict__ dB, int nB) {
  int i = blockIdx.x * 256 + threadIdx.x;
  const float* s;
  unsigned short* d;
  if (i < nA) {
    s = sA; d = dA;
  } else {
    i -= nA;
    if (i >= nB) return;
    s = sB; d = dB;
  }
  fl4 f = ((const fl4*)s)[i];
  us4 o;
  o[0] = f2bf(f[0]); o[1] = f2bf(f[1]); o[2] = f2bf(f[2]); o[3] = f2bf(f[3]);
  ((us4*)d)[i] = o;
}

// ---------------- transpose v: vT[b][c][t] = kqv[b*2048+t][2048+c] ----------------
__global__ __launch_bounds__(256) void transpose_v(const unsigned short* __restrict__ kqv,
                                                   unsigned short* __restrict__ vT) {
  int b = blockIdx.z;
  int t0 = blockIdx.x * 64;
  int c0 = blockIdx.y * 64;
  __shared__ unsigned short tile[64][68];
  int tid = threadIdx.x;
#pragma unroll
  for (int i = 0; i < 4; ++i) {
    int idx = i * 256 + tid;
    int r = idx >> 4;
    int c4 = (idx & 15) * 4;
    const unsigned short* src = kqv + ((size_t)(b * 2048 + t0 + r)) * 3072 + 2048 + c0 + c4;
    us4 v = *(const us4*)src;
    *(us4*)&tile[r][c4] = v;
  }
  __syncthreads();
#pragma unroll
  for (int i = 0; i < 4; ++i) {
    int idx = i * 256 + tid;
    int rc = idx >> 4;
    int t4 = (idx & 15) * 4;
    us4 v;
    v[0] = tile[t4 + 0][rc]; v[1] = tile[t4 + 1][rc];
    v[2] = tile[t4 + 2][rc]; v[3] = tile[t4 + 3][rc];
    unsigned short* dst = vT + ((size_t)(b * 1024 + c0 + rc)) * 2048 + t0 + t4;
    *(us4*)dst = v;
  }
}

// ---------------- g0: 128x384 8-phase GEMM, 512 blocks = 2 exact rounds -------
__global__ __launch_bounds__(512, 2) void gemm_g0(
    const unsigned short* __restrict__ A, const unsigned short* __restrict__ B,
    unsigned short* __restrict__ C, const float* __restrict__ bias) {
  const int flat = blockIdx.x;
  const int swz = (flat & 7) * 64 + (flat >> 3);   // XCD-contiguous remap
  const int bx = swz & 7;
  const int by = swz >> 3;
  const int rowBase = by * 128, colBase = bx * 384;
  const int lda = 1024, ldc = 3072, nk = 16;

  __shared__ __align__(16) unsigned char lds[131072];
  const int tid = threadIdx.x;
  const int lane = tid & 63, wid = tid >> 6;
  const int wr = wid >> 2, wc = wid & 3;
  const int l15 = lane & 15, l4 = lane >> 4, l7 = lane & 7;

  f32x4 acc[4][6] = {};
  bf16x8 af01[2][2], af23[2][2], bf[6][2];

  const unsigned short* Ab = A + (size_t)rowBase * lda;
  const unsigned short* Bb = B + (size_t)colBase * lda;
  unsigned aoff[2], boff[6], aldso[2], bldso[6];
#pragma unroll
  for (int i = 0; i < 6; ++i) {
    int off = i * 8192 + tid * 16;
    int r = off >> 7;
    int sb = ((off >> 4) & 7) ^ (r & 7);
    if (i < 2) { aoff[i] = (unsigned)(r * lda + sb * 8); aldso[i] = (unsigned)off; }
    boff[i] = (unsigned)(r * lda + sb * 8);
    bldso[i] = (unsigned)off;
  }

  auto STA = [&](int bufc, int op, int koff) {
    async16(Ab + (size_t)(aoff[op] + (unsigned)koff), lds + bufc * 65536 + aldso[op]);
  };
  auto STB = [&](int bufc, int op, int koff) {
    async16(Bb + (size_t)(boff[op] + (unsigned)koff),
            lds + bufc * 65536 + 16384 + bldso[op]);
  };
  auto RA = [&](int bufc, int m, int kk) -> bf16x8 {
    int row = wr * 64 + m * 16 + l15;
    int blk = (kk * 4 + l4) ^ l7;
    return *(const bf16x8*)(lds + bufc * 65536 + row * 128 + blk * 16);
  };
  auto RB = [&](int bufc, int n, int kk) -> bf16x8 {
    int row = wc * 96 + n * 16 + l15;
    int blk = (kk * 4 + l4) ^ l7;
    return *(const bf16x8*)(lds + bufc * 65536 + 16384 + row * 128 + blk * 16);
  };

#define RD_A01(BUF)                                                            \
  _Pragma("unroll") for (int mi = 0; mi < 2; ++mi)                             \
  _Pragma("unroll") for (int kk = 0; kk < 2; ++kk) af01[mi][kk] = RA((BUF), mi, kk)
#define RD_A23(BUF)                                                            \
  _Pragma("unroll") for (int mi = 0; mi < 2; ++mi)                             \
  _Pragma("unroll") for (int kk = 0; kk < 2; ++kk) af23[mi][kk] = RA((BUF), 2 + mi, kk)
#define RD_B(BUF, N0)                                                          \
  _Pragma("unroll") for (int nj = 0; nj < 3; ++nj)                             \
  _Pragma("unroll") for (int kk = 0; kk < 2; ++kk) bf[(N0) + nj][kk] = RB((BUF), (N0) + nj, kk)

#define MQ(MB, NB, AF)                                                         \
  _Pragma("unroll") for (int kk = 0; kk < 2; ++kk)                             \
  _Pragma("unroll") for (int mi = 0; mi < 2; ++mi)                             \
  _Pragma("unroll") for (int nj = 0; nj < 3; ++nj)                             \
      acc[(MB) + mi][(NB) + nj] = __builtin_amdgcn_mfma_f32_16x16x32_bf16(     \
          AF[mi][kk], bf[(NB) + nj][kk], acc[(MB) + mi][(NB) + nj], 0, 0, 0)

#define PHASE(RDS, STG, GATE, MB, NB, AF)                                      \
  do {                                                                         \
    RDS;                                                                       \
    STG;                                                                       \
    BARM();                                                                    \
    LGKM0();                                                                   \
    SCHEDB();                                                                  \
    __builtin_amdgcn_s_setprio(1);                                             \
    MQ(MB, NB, AF);                                                            \
    __builtin_amdgcn_s_setprio(0);                                             \
    GATE;                                                                      \
    BARM();                                                                    \
  } while (0)

  STA(0, 0, 0); STA(0, 1, 0);
#pragma unroll
  for (int i = 0; i < 6; ++i) STB(0, i, 0);
#pragma unroll
  for (int i = 0; i < 6; ++i) STB(1, i, 64);
  VMCNT6();
  BARM();

  for (int it = 0; it < 8; ++it) {
    int t = it * 2;
    int kA1 = (t + 1) * 64;
    int k2 = (t + 2 < nk - 1 ? t + 2 : nk - 1) * 64;
    int k3 = (t + 3 < nk - 1 ? t + 3 : nk - 1) * 64;
    PHASE({ RD_A01(0); RD_B(0, 0); }, { STA(1, 0, kA1); STA(1, 1, kA1); },
          (void)0, 0, 0, af01);
    PHASE({ RD_A23(0); RD_B(0, 3); }, (void)0, (void)0, 0, 3, af01);
    PHASE({}, { STB(0, 0, k2); STB(0, 1, k2); STB(0, 2, k2); },
          (void)0, 2, 3, af23);
    PHASE({}, { STB(0, 3, k2); STB(0, 4, k2); STB(0, 5, k2); },
          VMCNT6(), 2, 0, af23);
    PHASE({ RD_A01(1); RD_B(1, 0); }, { STA(0, 0, k2); STA(0, 1, k2); },
          (void)0, 0, 0, af01);
    PHASE({ RD_A23(1); RD_B(1, 3); }, (void)0, (void)0, 0, 3, af01);
    PHASE({}, { STB(1, 0, k3); STB(1, 1, k3); STB(1, 2, k3); },
          (void)0, 2, 3, af23);
    PHASE({}, { STB(1, 3, k3); STB(1, 4, k3); STB(1, 5, k3); },
          VMCNT6(), 2, 0, af23);
  }
#undef PHASE
#undef MQ
#undef RD_A01
#undef RD_A23
#undef RD_B

  const int cr = l4 * 4;
#pragma unroll
  for (int n = 0; n < 6; ++n) {
    int col = colBase + wc * 96 + n * 16 + l15;
    float bv = bias[col];
#pragma unroll
    for (int m = 0; m < 4; ++m) {
      int row = rowBase + wr * 64 + m * 16 + cr;
#pragma unroll
      for (int i = 0; i < 4; ++i)
        C[(size_t)(row + i) * ldc + col] = f2bf(acc[m][n][i] + bv);
    }
  }
}

// ---------------- g1: 256x256 8-phase GEMM, S = (k@q^T)*scale, causal skip ----
__global__ __launch_bounds__(512, 2) void gemm_s(
    const unsigned short* __restrict__ A, int lda, long long sA,
    const unsigned short* __restrict__ B, int ldb, long long sB,
    unsigned short* __restrict__ C, int ldc, long long sC,
    float scale, int K) {
  int bx = blockIdx.x, by = blockIdx.y;
  const int bz = blockIdx.z;
  if (bx > by) return;
  A += (size_t)bz * sA;
  B += (size_t)bz * sB;
  const int rowBase = by * 256;
  const int colBase = bx * 256;
  const int nk = K / 64;

  __shared__ __align__(16) unsigned char lds[131072];
  const int tid = threadIdx.x;
  const int lane = tid & 63;
  const int wid = tid >> 6;
  const int wr = wid >> 2;
  const int wc = wid & 3;
  const int l15 = lane & 15, l4 = lane >> 4, l7 = lane & 7;

  f32x4 acc[8][4] = {};
  bf16x8 af0[4][2], af1[4][2], bf0[2][2], bf1[2][2];

  const unsigned short* Ab = A + (size_t)rowBase * lda;
  const unsigned short* Bb = B + (size_t)colBase * ldb;
  unsigned loff[2][2];
  unsigned lldso[2];
#pragma unroll
  for (int i = 0; i < 2; ++i) {
    int off = (i * 512 + tid) * 16;
    int r = off >> 7;
    int sb = ((off >> 4) & 7) ^ (r & 7);
    lldso[i] = (unsigned)off;
#pragma unroll
    for (int hh = 0; hh < 2; ++hh)
      loff[hh][i] = (unsigned)((hh * 128 + r) * lda + sb * 8);
  }

  auto STAGE = [&](int bufc, int isB, int half, const unsigned short* Gb, int koff) {
#pragma unroll
    for (int i = 0; i < 2; ++i)
      async16(Gb + (size_t)(loff[half][i] + (unsigned)koff),
              lds + bufc * 65536 + isB * 32768 + half * 16384 + lldso[i]);
  };
  auto RDA = [&](int bufc, int m, int kk) -> bf16x8 {
    int row = m * 16 + l15;
    int blk = (kk * 4 + l4) ^ l7;
    return *(const bf16x8*)(lds + bufc * 65536 + wr * 16384 + row * 128 + blk * 16);
  };
  auto RDB = [&](int bufc, int n, int kk) -> bf16x8 {
    int row = (wc & 1) * 64 + n * 16 + l15;
    int blk = (kk * 4 + l4) ^ l7;
    return *(const bf16x8*)(lds + bufc * 65536 + 32768 + (wc >> 1) * 16384 +
                            row * 128 + blk * 16);
  };

#define RDA8(dst, BUF, Q)                                                      \
  _Pragma("unroll") for (int mi = 0; mi < 4; ++mi)                             \
  _Pragma("unroll") for (int kk = 0; kk < 2; ++kk)                             \
      dst[mi][kk] = RDA((BUF), (Q) * 4 + mi, kk)
#define RDB4(dst, BUF, NB)                                                     \
  _Pragma("unroll") for (int nj = 0; nj < 2; ++nj)                             \
  _Pragma("unroll") for (int kk = 0; kk < 2; ++kk)                             \
      dst[nj][kk] = RDB((BUF), (NB) + nj, kk)

#define MFMAQ(MB, NB, AF, BF)                                                  \
  _Pragma("unroll") for (int kk = 0; kk < 2; ++kk)                             \
  _Pragma("unroll") for (int mi = 0; mi < 4; ++mi)                             \
  _Pragma("unroll") for (int nj = 0; nj < 2; ++nj)                             \
      acc[(MB) + mi][(NB) + nj] = __builtin_amdgcn_mfma_f32_16x16x32_bf16(     \
          AF[mi][kk], BF[nj][kk], acc[(MB) + mi][(NB) + nj], 0, 0, 0)

#define PH(RDS, STG, HINT, GATE, MB, NB, AF, BF)                               \
  do {                                                                         \
    RDS;                                                                       \
    STG;                                                                       \
    HINT;                                                                      \
    BARM();                                                                    \
    LGKM0();                                                                   \
    SCHEDB();                                                                  \
    __builtin_amdgcn_s_setprio(1);                                             \
    MFMAQ(MB, NB, AF, BF);                                                     \
    __builtin_amdgcn_s_setprio(0);                                             \
    GATE;                                                                      \
    BARM();                                                                    \
  } while (0)

  STAGE(0, 0, 0, Ab, 0);
  STAGE(0, 0, 1, Ab, 0);
  STAGE(0, 1, 0, Bb, 0);
  STAGE(0, 1, 1, Bb, 0);
  STAGE(1, 1, 0, Bb, 64);
  STAGE(1, 1, 1, Bb, 64);
  VMCNT4();
  BARM();

  const int nt2 = nk >> 1;
  for (int it = 0; it < nt2; ++it) {
    int t = it * 2;
    int kA1 = (t + 1) * 64;
    int k2 = (t + 2 < nk - 1 ? t + 2 : nk - 1) * 64;
    int k3 = (t + 3 < nk - 1 ? t + 3 : nk - 1) * 64;
    PH({ RDA8(af0, 0, 0); RDB4(bf0, 0, 0); }, STAGE(1, 0, 0, Ab, kA1), LGKM8(),
       (void)0, 0, 0, af0, bf0);
    PH({ RDB4(bf1, 0, 2); }, STAGE(1, 0, 1, Ab, kA1), (void)0,
       (void)0, 0, 2, af0, bf1);
    PH({ RDA8(af1, 0, 1); }, STAGE(0, 1, 0, Bb, k2), (void)0,
       (void)0, 4, 2, af1, bf1);
    PH({}, STAGE(0, 1, 1, Bb, k2), (void)0,
       VMCNT4(), 4, 0, af1, bf0);
    PH({ RDA8(af0, 1, 0); RDB4(bf0, 1, 0); }, STAGE(0, 0, 0, Ab, k2), LGKM8(),
       (void)0, 0, 0, af0, bf0);
    PH({ RDB4(bf1, 1, 2); }, STAGE(0, 0, 1, Ab, k2), (void)0,
       (void)0, 0, 2, af0, bf1);
    PH({ RDA8(af1, 1, 1); }, STAGE(1, 1, 0, Bb, k3), (void)0,
       (void)0, 4, 2, af1, bf1);
    PH({}, STAGE(1, 1, 1, Bb, k3), (void)0,
       VMCNT4(), 4, 0, af1, bf0);
  }
#undef PH
#undef MFMAQ
#undef RDA8
#undef RDB4

  const int cr = l4 * 4;
  unsigned short* Cb = C + (size_t)bz * sC;
#pragma unroll
  for (int n = 0; n < 4; ++n) {
    int col = colBase + wc * 64 + n * 16 + l15;
#pragma unroll
    for (int m = 0; m < 8; ++m) {
      int row = rowBase + wr * 128 + m * 16 + cr;
#pragma unroll
      for (int i = 0; i < 4; ++i)
        Cb[(size_t)(row + i) * ldc + col] = f2bf(acc[m][n][i] * scale);
    }
  }
}

// ---------------- g2: two-chain pv — uniform 34 K-tiles per block -------------
__global__ __launch_bounds__(256, 2) void gemm_pv2(
    const unsigned short* __restrict__ S, const unsigned short* __restrict__ V,
    float* __restrict__ O) {
  const int f = blockIdx.x;
  const int bx = f & 7;
  const int p = (f >> 3) & 7;
  const int bz = f >> 6;
  const int byH = 15 - p;
  const int nkL = 2 * (p + 1);
  const int nkH = 32 - 2 * p;
  const unsigned short* base = S + (size_t)bz * 2048 * 2048;
  const unsigned short* AH = base + (size_t)(byH * 128) * 2048;
  const unsigned short* AL = base + (size_t)(p * 128) * 2048;
  const unsigned short* Bb = V + (size_t)bz * 1024 * 2048 + (size_t)(bx * 128) * 2048;
  float* Ob = O + (size_t)bz * 2048 * 1024;

  __shared__ __align__(16) unsigned char lds[65536];
  const int tid = threadIdx.x;
  const int lane = tid & 63, wid = tid >> 6;
  const int wr = (wid >> 1) * 64, wc = (wid & 1) * 64;
  const int l15 = lane & 15, l4 = lane >> 4, l7 = lane & 7;

  f32x4 accH[4][4] = {}, accL[4][4] = {};

  unsigned goff[4], ldso[4];
#pragma unroll
  for (int ii = 0; ii < 4; ++ii) {
    int off = (ii * 256 + tid) * 16;
    int rr = off >> 7;
    int sb = ((off >> 4) & 7) ^ (rr & 7);
    goff[ii] = (unsigned)(rr * 2048 + sb * 8);
    ldso[ii] = (unsigned)off;
  }

  auto ST = [&](int buf, const unsigned short* Ap, unsigned kof) {
#pragma unroll
    for (int ii = 0; ii < 4; ++ii) {
      async16(Ap + (size_t)(goff[ii] + kof), lds + buf * 32768 + ldso[ii]);
      async16(Bb + (size_t)(goff[ii] + kof), lds + buf * 32768 + 16384 + ldso[ii]);
    }
  };
  auto ITEM = [&](int i, const unsigned short*& P, unsigned& kf) {
    if (i < 2 * nkL) {
      P = (i & 1) ? AL : AH;
      kf = (unsigned)((i >> 1) * 64);
    } else {
      P = AH;
      kf = (unsigned)((i - nkL) * 64);
    }
  };

#define PVSTEP(BUF, ACC, NITEM)                                                \
  do {                                                                         \
    const unsigned short* nP;                                                  \
    unsigned nK;                                                               \
    ITEM((NITEM) < 33 ? (NITEM) : 33, nP, nK);                                 \
    VMCNT8();                                                                  \
    BARM();                                                                    \
    bf16x8 af[4][2], bfr[4][2];                                                \
    _Pragma("unroll") for (int m = 0; m < 4; ++m) {                            \
      int row = wr + m * 16 + l15;                                             \
      _Pragma("unroll") for (int kk = 0; kk < 2; ++kk)                         \
        af[m][kk] = *(const bf16x8*)(lds + (BUF) * 32768 + row * 128 +         \
                                     (((kk * 4 + l4) ^ l7) * 16));             \
    }                                                                          \
    _Pragma("unroll") for (int n = 0; n < 4; ++n) {                            \
      int row = wc + n * 16 + l15;                                             \
      _Pragma("unroll") for (int kk = 0; kk < 2; ++kk)                         \
        bfr[n][kk] = *(const bf16x8*)(lds + (BUF) * 32768 + 16384 + row * 128 +\
                                      (((kk * 4 + l4) ^ l7) * 16));            \
    }                                                                          \
    LGKM0();                                                                   \
    BARM();                                                                    \
    ST((BUF), nP, nK);                                                         \
    SCHEDB();                                                                  \
    __builtin_amdgcn_s_setprio(1);                                             \
    _Pragma("unroll") for (int kk = 0; kk < 2; ++kk)                           \
    _Pragma("unroll") for (int m = 0; m < 4; ++m)                              \
    _Pragma("unroll") for (int n = 0; n < 4; ++n)                              \
      ACC[m][n] = __builtin_amdgcn_mfma_f32_16x16x32_bf16(af[m][kk], bfr[n][kk],\
                                                          ACC[m][n], 0, 0, 0); \
    __builtin_amdgcn_s_setprio(0);                                             \
  } while (0)

  ST(0, AH, 0);
  {
    const unsigned short* P; unsigned kf;
    ITEM(1, P, kf);
    ST(1, P, kf);
  }

  for (int t = 0; t < nkL; ++t) {
    PVSTEP(0, accH, 2 * t + 2);
    PVSTEP(1, accL, 2 * t + 3);
  }
  for (int u = nkL; u < nkH; u += 2) {
    PVSTEP(0, accH, u + nkL + 2);
    PVSTEP(1, accH, u + nkL + 3);
  }
#undef PVSTEP

  const int cr = l4 * 4;
#pragma unroll
  for (int n = 0; n < 4; ++n) {
    int col = bx * 128 + wc + n * 16 + l15;
#pragma unroll
    for (int m = 0; m < 4; ++m) {
      int rH = byH * 128 + wr + m * 16 + cr;
      int rL = p * 128 + wr + m * 16 + cr;
#pragma unroll
      for (int i = 0; i < 4; ++i) {
        Ob[(size_t)(rH + i) * 1024 + col] = accH[m][n][i];
        Ob[(size_t)(rL + i) * 1024 + col] = accL[m][n][i];
      }
    }
  }
}

// ---------------- causal softmax over S rows (in place, bf16) ----------------
__global__ __launch_bounds__(256) void softmax_causal(unsigned short* __restrict__ S) {
  const int T = 2048;
  int t = blockIdx.x, b = blockIdx.y;
  unsigned short* row = S + ((size_t)b * T + t) * T;
  const int nv = t + 1;
  const int bound = ((t >> 7) + 1) << 7;
  int tid = threadIdx.x;
  int lane = tid & 63, wid = tid >> 6;
  int s0 = tid * 8;
  us8 raw = {};
  if (s0 < nv) raw = *(const us8*)(row + s0);
  float v[8];
  float m = -3.0e38f;
#pragma unroll
  for (int j = 0; j < 8; ++j) {
    v[j] = bf2f(raw[j]);
    if (s0 + j < nv) m = fmaxf(m, v[j]);
  }
#pragma unroll
  for (int o = 32; o > 0; o >>= 1) m = fmaxf(m, __shfl_xor(m, o, 64));
  __shared__ float red[4];
  if (lane == 0) red[wid] = m;
  __syncthreads();
  m = fmaxf(fmaxf(red[0], red[1]), fmaxf(red[2], red[3]));
  __syncthreads();
  float sum = 0.f;
#pragma unroll
  for (int j = 0; j < 8; ++j) {
    float e = (s0 + j < nv) ? exp2f(v[j] - m) : 0.f;
    v[j] = e;
    sum += e;
  }
#pragma unroll
  for (int o = 32; o > 0; o >>= 1) sum += __shfl_xor(sum, o, 64);
  if (lane == 0) red[wid] = sum;
  __syncthreads();
  sum = red[0] + red[1] + red[2] + red[3];
  float inv = 1.0f / sum;
  if (s0 < bound) {
    us8 outv;
#pragma unroll
    for (int j = 0; j < 8; ++j) outv[j] = f2bf(v[j] * inv);
    *(us8*)(row + s0) = outv;
  }
}

extern "C" void kernel_launch(void* const* d_in, const int* in_sizes, int n_in,
                              void* d_out, int out_size, void* d_ws, size_t ws_size,
                              hipStream_t stream) {
  const float* x = (const float*)d_in[0];      // [4,2048,1024]
  const float* W = (const float*)d_in[1];      // [3072,1024]
  const float* bias = (const float*)d_in[2];   // [3072]
  float* out = (float*)d_out;                  // [4,2048,1024]

  char* ws = (char*)d_ws;
  if (ws_size < 106954752u) return;
  unsigned short* xbf = (unsigned short*)(ws);
  unsigned short* vT = xbf;  // alias: xbf dead after gemm_g0
  unsigned short* wbf = (unsigned short*)(ws + 16777216);
  unsigned short* kqv = (unsigned short*)(ws + 23068672);
  unsigned short* S = (unsigned short*)(ws + 73400320);

  const float kSoftmaxScale = 1.4426950408889634f / 32.0f;  // log2(e)/sqrt(1024)

  cvt_bf16_2<<<11264, 256, 0, stream>>>(x, xbf, 2097152, W, wbf, 786432);

  // kqv = x @ W^T + b : 128x384 tiles, 8x64 = 512 blocks = 2 exact rounds
  gemm_g0<<<dim3(512, 1, 1), 512, 0, stream>>>(xbf, wbf, kqv, bias);

  transpose_v<<<dim3(32, 16, 4), 256, 0, stream>>>(kqv, vT);

  // S = (k @ q^T) * log2e/32 (bf16), causal blocks skipped
  gemm_s<<<dim3(8, 8, 4), 512, 0, stream>>>(
      kqv, 3072, 2048LL * 3072, kqv + 1024, 3072, 2048LL * 3072,
      S, 2048, 2048LL * 2048, kSoftmaxScale, 1024);

  softmax_causal<<<dim3(2048, 4), 256, 0, stream>>>(S);

  // out = P @ vT^T (fp32): two-chain blocks, uniform 34 K-tiles, 256 = 1/CU
  gemm_pv2<<<dim3(256, 1, 1), 256, 0, stream>>>(S, vT, out);
}